// Round 7
// baseline (331.237 us; speedup 1.0000x reference)
//
#include <hip/hip_runtime.h>
#include <hip/hip_bf16.h>
#include <hip/hip_cooperative_groups.h>

namespace cg = cooperative_groups;

#define TOTAL_N   131072
#define NEDGE     4194304
#define NPG       2048
#define IN_DIM_K  128
#define HID_K     256
#define EMB_K     64
#define NAGENT    64

#define F1CAP     4096
#define E1CAP     98304
#define APACK     128

#define NBLK      256
#define NTHR      1024
#define EPB1      (NEDGE / NBLK)     // 16384 edges per block per scan
#define HWORDS    (TOTAL_N / 8)      // 16384 nibble-packed u32 words
#define E1BUF     768                // per-block hit buffer (mean 256)

#define DYN_LDS   86016              // 84 KB

// ---------------- workspace layout (bytes) ----------------
// memset every launch [0, 18432):
//   0        counters int[256]        ([1]=nF1 [2]=nE1)
//   1024     e0cnt    int[64]
//   2048     bitmap   u32[4096]       16K (F1 membership; atomicOr in phase 1)
// zeroed in-kernel (phase 2): inF1, agg1
//   18432    inF1     int[4096]       16K
//   34816    loc      int[131072]     512K  (phase 2 writes all)
//   559104   e0pack   int[64*128]     32K
//   591872   e1pack   int[E1CAP]      384K  ((l<<17)|s)
//   984064   es_pack  int[E1CAP]      384K  (dst-sorted)
//   1376256  out_deg  u32[131072]     512K
//   1900544  wswz     u16[32768]      64K
//   1966080  cursor   int[4096]       16K
//   1982464  agg1     f32[4096*256]   4M
//   6176768  h1       f32[4096*256]   4M
//   10371072 partial  u32[256*16384]  16M
// total ~25 MB

typedef float f32x4 __attribute__((ext_vector_type(4)));
typedef short bf16x8 __attribute__((ext_vector_type(8)));

__device__ inline unsigned short f2bf(float f) {   // RNE f32->bf16
    unsigned int u = __float_as_uint(f);
    return (unsigned short)((u + 0x7FFFu + ((u >> 16) & 1u)) >> 16);
}

__global__ __launch_bounds__(NTHR) void k_mega(
    const float* __restrict__ x, const int* __restrict__ src,
    const int* __restrict__ dst,
    const float* __restrict__ wlin, const float* __restrict__ blin,
    const float* __restrict__ wc0, const float* __restrict__ bc0,
    const float* __restrict__ wc1, const float* __restrict__ bc1,
    const float* __restrict__ wemb, const float* __restrict__ bemb,
    float* __restrict__ out, char* __restrict__ ws)
{
    extern __shared__ char smem[];
    cg::grid_group grid = cg::this_grid();
    const int t = threadIdx.x;
    const int b = blockIdx.x;

    int*            counters = (int*)(ws);
    int*            e0cnt    = (int*)(ws + 1024);
    unsigned int*   bitmap   = (unsigned int*)(ws + 2048);
    int*            inF1     = (int*)(ws + 18432);
    int*            loc      = (int*)(ws + 34816);
    int*            e0pack   = (int*)(ws + 559104);
    int*            e1pack   = (int*)(ws + 591872);
    int*            es_pack  = (int*)(ws + 984064);
    unsigned int*   out_deg  = (unsigned int*)(ws + 1376256);
    unsigned short* wswz     = (unsigned short*)(ws + 1900544);
    int*            cursor   = (int*)(ws + 1966080);
    float*          agg1     = (float*)(ws + 1982464);
    float*          h1       = (float*)(ws + 6176768);
    unsigned int*   partial  = (unsigned int*)(ws + 10371072);

    // ============ phase 1: edge scan 1 — out-deg nibble hist + e0/F1 marking ============
    {
        unsigned int* hist = (unsigned int*)smem;   // 64 KB
        #pragma unroll
        for (int i = 0; i < HWORDS / NTHR; i++) hist[t + i * NTHR] = 0u;
        __syncthreads();
        const int ebase = b * EPB1;
        const int4* s4 = (const int4*)(src + ebase);
        const int4* d4 = (const int4*)(dst + ebase);
        #pragma unroll
        for (int i = 0; i < EPB1 / (4 * NTHR); i++) {   // 4 iterations
            int4 sv = s4[i * NTHR + t];
            int4 dv = d4[i * NTHR + t];
            int ss[4] = {sv.x, sv.y, sv.z, sv.w};
            int dd[4] = {dv.x, dv.y, dv.z, dv.w};
            #pragma unroll
            for (int j = 0; j < 4; j++) {
                int s = ss[j], d = dd[j];
                atomicAdd(&hist[s >> 3], 1u << ((s & 7) * 4));
                if ((d & (NPG - 1)) == 0) {
                    atomicOr(&bitmap[s >> 5], 1u << (s & 31));
                    int a = d >> 11;
                    int sl = atomicAdd(&e0cnt[a], 1);
                    if (sl < APACK) e0pack[a * APACK + sl] = s;
                }
            }
        }
        __syncthreads();
        unsigned int* po = partial + b * HWORDS;
        #pragma unroll
        for (int i = 0; i < HWORDS / NTHR; i++) po[t + i * NTHR] = hist[t + i * NTHR];
    }
    grid.sync();

    // ============ phase 2: compact+wprep+zero (blocks<128) | deg-reduce+agg1-zero ============
    if (b < 128) {
        int* cnt   = (int*)smem;
        int* gbase = (int*)smem + 1;
        if (t == 0) *cnt = 0;
        __syncthreads();
        int v = b * NTHR + t;
        int bit = (bitmap[v >> 5] >> (v & 31)) & 1u;
        int p = -1;
        if (bit) p = atomicAdd(cnt, 1);
        __syncthreads();
        if (t == 0) *gbase = (*cnt) ? atomicAdd(&counters[1], *cnt) : 0;
        __syncthreads();
        int l = -1;
        if (p >= 0) { int id = *gbase + p; if (id < F1CAP) l = id; }
        loc[v] = l;
        if (b < 4) {          // wprep: wlin -> bf16 MFMA B-frag order
            int g = b * NTHR + t;                    // 4096 items
            int lane = g & 63, ct = (g >> 6) & 15, kt = g >> 10;
            int colbase = ct * 16 + (lane & 15);
            int kbase = kt * 32 + (lane >> 4) * 8;
            unsigned short o[8];
            #pragma unroll
            for (int i = 0; i < 8; i++) o[i] = f2bf(wlin[(kbase + i) * HID_K + colbase]);
            *(ushort4*)(wswz + g * 8)     = make_ushort4(o[0], o[1], o[2], o[3]);
            *(ushort4*)(wswz + g * 8 + 4) = make_ushort4(o[4], o[5], o[6], o[7]);
        } else if (b == 4) {  // zero inF1
            #pragma unroll
            for (int i = 0; i < F1CAP / NTHR; i++) inF1[t + i * NTHR] = 0;
        }
    } else {
        // out_deg reduce: 128 blocks x 128 words; 8 g-slices x 32 summands/thread
        int wl = t & 127, gs = t >> 7;
        int w = (b - 128) * 128 + wl;
        unsigned int accE = 0, accO = 0;
        #pragma unroll 8
        for (int i = 0; i < 32; i++) {
            unsigned int v = partial[(gs * 32 + i) * HWORDS + w];
            accE += v & 0x0F0F0F0Fu;
            accO += (v >> 4) & 0x0F0F0F0Fu;
        }
        unsigned int* redE = (unsigned int*)smem;          // [8][128]
        unsigned int* redO = (unsigned int*)smem + 1024;   // [8][128]
        redE[gs * 128 + wl] = accE;
        redO[gs * 128 + wl] = accO;
        __syncthreads();
        if (gs == 0) {
            unsigned int sE = 0, sO = 0;
            #pragma unroll
            for (int k2 = 0; k2 < 8; k2++) { sE += redE[k2 * 128 + wl]; sO += redO[k2 * 128 + wl]; }
            uint4 lo = make_uint4(sE & 255u, sO & 255u, (sE >> 8) & 255u, (sO >> 8) & 255u);
            uint4 hi = make_uint4((sE >> 16) & 255u, (sO >> 16) & 255u, (sE >> 24) & 255u, (sO >> 24) & 255u);
            ((uint4*)(out_deg + 8 * w))[0] = lo;
            ((uint4*)(out_deg + 8 * w))[1] = hi;
        }
        // zero agg1: 4 MB over 128 blocks = 2048 float4 each
        float4 z = make_float4(0.f, 0.f, 0.f, 0.f);
        float4* a4 = (float4*)agg1 + (long long)(b - 128) * 2048;
        a4[t] = z;
        a4[t + 1024] = z;
    }
    grid.sync();

    // ============ phase 3: edge scan 2 — select edges with dst in F1 ============
    {
        unsigned int* bm  = (unsigned int*)smem;            // 16 KB
        int* buf   = (int*)(smem + 16384);                  // E1BUF
        int* cnt   = (int*)(smem + 16384 + E1BUF * 4);
        int* gbase = cnt + 1;
        ((uint4*)bm)[t] = ((const uint4*)bitmap)[t];        // 1024 uint4
        if (t == 0) *cnt = 0;
        __syncthreads();
        const int ebase = b * EPB1;
        const int4* d4p = (const int4*)(dst + ebase);
        #pragma unroll
        for (int i = 0; i < EPB1 / (4 * NTHR); i++) {       // 4 iterations
            int4 dv = d4p[i * NTHR + t];
            int eidx = ebase + (i * NTHR + t) * 4;
            int dd[4] = {dv.x, dv.y, dv.z, dv.w};
            #pragma unroll
            for (int j = 0; j < 4; j++) {
                int d = dd[j];
                if ((bm[d >> 5] >> (d & 31)) & 1u) {
                    int l = loc[d];
                    if (l >= 0) {
                        atomicAdd(&inF1[l], 1);
                        int s = src[eidx + j];
                        int pk = (l << 17) | s;
                        int p = atomicAdd(cnt, 1);
                        if (p < E1BUF) buf[p] = pk;
                        else {
                            int gi = atomicAdd(&counters[2], 1);
                            if (gi < E1CAP) e1pack[gi] = pk;
                        }
                    }
                }
            }
        }
        __syncthreads();
        int c = min(*cnt, E1BUF);
        if (t == 0) *gbase = c ? atomicAdd(&counters[2], c) : 0;
        __syncthreads();
        if (t < c) { int idx = *gbase + t; if (idx < E1CAP) e1pack[idx] = buf[t]; }
    }
    grid.sync();

    // ============ phase 4: exclusive scan inF1 -> cursor (block 0) ============
    if (b == 0) {
        int* a  = (int*)smem;
        int* bb = (int*)(smem + 16384);
        int nF1 = min(counters[1], F1CAP);
        for (int i = t; i < F1CAP; i += NTHR) a[i] = (i < nF1) ? inF1[i] : 0;
        __syncthreads();
        int* sp = a; int* dp = bb;
        for (int off = 1; off < F1CAP; off <<= 1) {
            for (int i = t; i < F1CAP; i += NTHR)
                dp[i] = (i >= off) ? sp[i] + sp[i - off] : sp[i];
            __syncthreads();
            int* tmp = sp; sp = dp; dp = tmp;
        }
        for (int i = t; i < F1CAP; i += NTHR) cursor[i] = (i == 0) ? 0 : sp[i - 1];
    }
    grid.sync();

    // ============ phase 5: scatter into dst-sorted slots ============
    {
        int nE1 = min(counters[2], E1CAP);
        int i = b * NTHR + t;
        if (i < nE1) {
            int pk = e1pack[i];
            int l = pk >> 17;
            int slot = atomicAdd(&cursor[l], 1);
            if (slot < E1CAP) es_pack[slot] = pk;
        }
    }
    grid.sync();

    // ============ phase 6: MFMA edge-GEMM + segmented reduce (64-row tiles) ============
    {
        unsigned short* A = (unsigned short*)smem;          // [64][136] bf16
        float* T    = (float*)(smem + 17408);               // [64][257] f32
        int*   rsrc = (int*)(smem + 83200);
        int*   rdst = (int*)(smem + 83456);
        float* escs = (float*)(smem + 83712);
        int nE1 = min(counters[2], E1CAP);
        int ntiles = (nE1 + 63) >> 6;
        const int lane = t & 63, wq = t >> 6;
        const int mg = wq >> 2, cgp = wq & 3;
        for (int ti = b; ti < ntiles; ti += NBLK) {
            int base = ti * 64;
            if (t < 64) {
                int row = base + t; int s = -1, d = -1; float e = 0.f;
                if (row < nE1) {
                    int pk = es_pack[row];
                    s = pk & 0x1FFFF; d = pk >> 17;
                    e = rsqrtf((float)max((int)out_deg[s], 1));
                }
                rsrc[t] = s; rdst[t] = d; escs[t] = e;
            }
            __syncthreads();
            #pragma unroll
            for (int i = 0; i < 2; i++) {                  // gather 64 x-rows -> bf16
                int idx = t + i * NTHR;
                int r = idx >> 5, q = idx & 31;
                int s = rsrc[r];
                float4 v = make_float4(0.f, 0.f, 0.f, 0.f);
                if (s >= 0) v = ((const float4*)(x + (long long)s * IN_DIM_K))[q];
                ushort4 h;
                h.x = f2bf(v.x); h.y = f2bf(v.y); h.z = f2bf(v.z); h.w = f2bf(v.w);
                *(ushort4*)&A[r * 136 + q * 4] = h;
            }
            __syncthreads();
            f32x4 acc[4];
            #pragma unroll
            for (int n = 0; n < 4; n++) acc[n] = (f32x4){0.f, 0.f, 0.f, 0.f};
            #pragma unroll
            for (int kt = 0; kt < 4; kt++) {
                bf16x8 af = *(const bf16x8*)&A[(mg * 16 + (lane & 15)) * 136 + kt * 32 + (lane >> 4) * 8];
                #pragma unroll
                for (int n = 0; n < 4; n++) {
                    bf16x8 bf = *(const bf16x8*)(wswz + ((kt * 16 + cgp * 4 + n) * 64 + lane) * 8);
                    acc[n] = __builtin_amdgcn_mfma_f32_16x16x32_bf16(af, bf, acc[n], 0, 0, 0);
                }
            }
            int cbase = lane & 15, rgrp = (lane >> 4) * 4;
            #pragma unroll
            for (int n = 0; n < 4; n++) {
                float bj = blin[cgp * 64 + n * 16 + cbase];
                #pragma unroll
                for (int j = 0; j < 4; j++) {
                    int row = mg * 16 + rgrp + j;
                    T[row * 257 + cgp * 64 + n * 16 + cbase] =
                        fmaxf(acc[n][j] + bj, 0.f) * escs[row];
                }
            }
            __syncthreads();
            if (t < HID_K) {                               // segmented reduce, col t
                float segs = 0.f; int cur = rdst[0];
                for (int r = 0; r < 64; r++) {
                    int d = rdst[r];
                    if (d != cur) {
                        if (cur >= 0) atomicAdd(&agg1[cur * HID_K + t], segs);
                        segs = 0.f; cur = d;
                    }
                    segs += T[r * 257 + t];
                }
                if (cur >= 0) atomicAdd(&agg1[cur * HID_K + t], segs);
            }
            __syncthreads();
        }
    }
    grid.sync();

    // ============ phase 7: h1 = relu((agg1*in_norm)@wc0 + bc0), 8-row tiles ============
    {
        float* ns = (float*)smem;                 // [8]
        float* as = (float*)(smem + 1024);        // [8][260]
        int nF1 = min(counters[1], F1CAP);
        int ntile = (nF1 + 7) >> 3;
        for (int ti = b; ti < ntile; ti += NBLK) {
            int base = ti * 8;
            if (t < 8) ns[t] = (base + t < nF1) ? rsqrtf((float)max(inF1[base + t], 1)) : 0.f;
            __syncthreads();
            if (t < 512) {
                int r = t >> 6, q = t & 63;
                int l = base + r;
                float4 v = make_float4(0.f, 0.f, 0.f, 0.f);
                if (l < nF1) v = ((const float4*)(agg1 + (long long)l * HID_K))[q];
                float sc = ns[r];
                v.x *= sc; v.y *= sc; v.z *= sc; v.w *= sc;
                *(float4*)&as[r * 260 + q * 4] = v;
            }
            __syncthreads();
            int j = t & 255, rg = t >> 8;          // rows rg*2, rg*2+1
            float a0 = 0.f, a1 = 0.f;
            for (int k = 0; k < HID_K; k += 4) {
                float w0 = wc0[(k + 0) * HID_K + j];
                float w1 = wc0[(k + 1) * HID_K + j];
                float w2 = wc0[(k + 2) * HID_K + j];
                float w3 = wc0[(k + 3) * HID_K + j];
                float4 v0 = *(const float4*)&as[(rg * 2) * 260 + k];
                float4 v1 = *(const float4*)&as[(rg * 2 + 1) * 260 + k];
                a0 = fmaf(v0.x, w0, a0); a0 = fmaf(v0.y, w1, a0);
                a0 = fmaf(v0.z, w2, a0); a0 = fmaf(v0.w, w3, a0);
                a1 = fmaf(v1.x, w0, a1); a1 = fmaf(v1.y, w1, a1);
                a1 = fmaf(v1.z, w2, a1); a1 = fmaf(v1.w, w3, a1);
            }
            float bj = bc0[j];
            int r0 = base + rg * 2, r1 = r0 + 1;
            if (r0 < nF1) h1[(long long)r0 * HID_K + j] = fmaxf(a0 + bj, 0.f);
            if (r1 < nF1) h1[(long long)r1 * HID_K + j] = fmaxf(a1 + bj, 0.f);
            __syncthreads();
        }
    }
    grid.sync();

    // ============ phase 8: per-agent aggregate + 2 GEMMs ============
    if (b < NAGENT) {
        float* a_s = (float*)smem;
        float* h2  = (float*)(smem + 1024);
        int*   ls  = (int*)(smem + 2048);
        float* scs = (float*)(smem + 2560);
        int n0 = e0cnt[b];
        int ne = min(n0, APACK);
        if (t < ne) {
            int s = e0pack[b * APACK + t];
            int l = loc[s];
            ls[t] = l;
            scs[t] = (l >= 0) ? rsqrtf((float)max((int)out_deg[s], 1)) : 0.f;
        }
        __syncthreads();
        if (t < HID_K) {
            float acc = 0.f;
            for (int i = 0; i < ne; i++) {
                int l = ls[i];
                if (l >= 0) acc = fmaf(scs[i], h1[(long long)l * HID_K + t], acc);
            }
            a_s[t] = acc * rsqrtf((float)max(n0, 1));
        }
        __syncthreads();
        if (t < HID_K) {
            float h = 0.f;
            for (int k = 0; k < HID_K; k++)
                h = fmaf(a_s[k], wc1[k * HID_K + t], h);
            h2[t] = fmaxf(h + bc1[t], 0.f);
        }
        __syncthreads();
        if (t < EMB_K) {
            float o = bemb[t];
            for (int k = 0; k < HID_K; k++)
                o = fmaf(h2[k], wemb[k * EMB_K + t], o);
            out[b * EMB_K + t] = o;
        }
    }
}

extern "C" void kernel_launch(void* const* d_in, const int* in_sizes, int n_in,
                              void* d_out, int out_size, void* d_ws, size_t ws_size,
                              hipStream_t stream)
{
    const float* x    = (const float*)d_in[0];
    const int*   src  = (const int*)d_in[1];
    const int*   dst  = (const int*)d_in[2];
    const float* wlin = (const float*)d_in[5];
    const float* blin = (const float*)d_in[6];
    const float* wc0  = (const float*)d_in[7];
    const float* bc0  = (const float*)d_in[8];
    const float* wc1  = (const float*)d_in[9];
    const float* bc1  = (const float*)d_in[10];
    const float* wemb = (const float*)d_in[11];
    const float* bemb = (const float*)d_in[12];
    float* out = (float*)d_out;
    char* ws = (char*)d_ws;

    static int attr_set = 0;   // host-side only; idempotent, deterministic
    if (!attr_set) {
        hipFuncSetAttribute((const void*)k_mega,
                            hipFuncAttributeMaxDynamicSharedMemorySize, DYN_LDS);
        attr_set = 1;
    }

    hipMemsetAsync(ws, 0, 18432, stream);

    void* args[] = {(void*)&x, (void*)&src, (void*)&dst,
                    (void*)&wlin, (void*)&blin, (void*)&wc0, (void*)&bc0,
                    (void*)&wc1, (void*)&bc1, (void*)&wemb, (void*)&bemb,
                    (void*)&out, (void*)&ws};
    hipLaunchCooperativeKernel((const void*)k_mega, dim3(NBLK), dim3(NTHR),
                               args, DYN_LDS, stream);
}

// Round 9
// 152.827 us; speedup vs baseline: 2.1674x; 2.1674x over previous
//
#include <hip/hip_runtime.h>
#include <hip/hip_bf16.h>

#define TOTAL_N   131072
#define NEDGE     4194304
#define NPG       2048
#define IN_DIM_K  128
#define HID_K     256
#define EMB_K     64
#define NAGENT    64

#define F1CAP     4096
#define E1CAP     98304      // 1.5x expected nE1 (~65K)
#define APACK     128        // per-agent e0 slot cap (mean 32, Poisson tail safe)

#define G1        256                 // k_outdeg_e0 blocks (1/CU, full chip)
#define EPB1      (NEDGE / G1)        // 16384 edges per block
#define HWORDS    (TOTAL_N / 8)       // 16384 nibble-packed u32 words

#define SCAN_BLOCKS 2048
#define EPB         2048              // NEDGE / SCAN_BLOCKS
#define E1BUF       256               // per-block hit buffer (mean 32 hits)

// ---------------- workspace layout (bytes), ws_size = 256 MiB ----------------
// zeroed every launch [0, 4784128):
//   0        counters  int[256]        ([1]=nF1 [2]=nE1)
//   1024     inF1      int[F1CAP]      16K
//   17408    e0cnt     int[64]         256B  (= agent in-degree)
//   65536    flag      int[TOTAL_N]    512K
//   589824   agg1      float[F1CAP*HID] 4M
// not zeroed (fully written before read):
//   4784128  loc       int[TOTAL_N]    512K
//   5308416  e0pack    int[64*APACK]   32K
//   5341184  e1src     int[E1CAP]      384K
//   5734400  e1loc     int[E1CAP]      384K
//   6127616  out_deg   u32[TOTAL_N]    512K
//   6651904  wswz      u16[32768]      64K
//   6717440  cursor    int[F1CAP]      16K
//   6733824  bitmap    u64[2048]       16K
//   6750208  partial   u32[G1*HWORDS]  16M
//   23527424 h1        float[F1CAP*HID] 4M
//   27721728 es_pack   int[E1CAP]      384K
// total ~28.1 MB

#define ZERO_SPAN 4784128

typedef float f32x4 __attribute__((ext_vector_type(4)));
typedef short bf16x8 __attribute__((ext_vector_type(8)));

__device__ inline unsigned short f2bf(float f) {   // RNE f32->bf16
    unsigned int u = __float_as_uint(f);
    return (unsigned short)((u + 0x7FFFu + ((u >> 16) & 1u)) >> 16);
}

// K1: out-degree nibble histogram (full chip) + e0 select into per-agent buckets
__global__ __launch_bounds__(1024) void k_outdeg_e0(
    const int* __restrict__ src, const int* __restrict__ dst,
    unsigned int* __restrict__ partial,
    int* __restrict__ flag,
    int* __restrict__ e0pack, int* __restrict__ e0cnt)
{
    __shared__ unsigned int hist[HWORDS];   // 64 KB
    int t = threadIdx.x;
    #pragma unroll
    for (int i = 0; i < HWORDS / 1024; i++) hist[t + i * 1024] = 0u;
    __syncthreads();

    int ebase = blockIdx.x * EPB1;
    const int4* s4 = (const int4*)(src + ebase);
    const int4* d4 = (const int4*)(dst + ebase);
    #pragma unroll
    for (int i = 0; i < EPB1 / 4096; i++) {     // 4 iterations
        int4 sv = s4[i * 1024 + t];
        int4 dv = d4[i * 1024 + t];
        int ss[4] = {sv.x, sv.y, sv.z, sv.w};
        int dd[4] = {dv.x, dv.y, dv.z, dv.w};
        #pragma unroll
        for (int j = 0; j < 4; j++) {
            int s = ss[j], d = dd[j];
            atomicAdd(&hist[s >> 3], 1u << ((s & 7) * 4));
            if ((d & (NPG - 1)) == 0) {
                flag[s] = 1;                     // idempotent race
                int a = d >> 11;
                int slot = atomicAdd(&e0cnt[a], 1);   // 64 hot L2 addrs, ~2K total
                if (slot < APACK) e0pack[a * APACK + slot] = s;
            }
        }
    }
    __syncthreads();
    unsigned int* pout = partial + blockIdx.x * HWORDS;
    #pragma unroll
    for (int i = 0; i < HWORDS / 1024; i++) pout[t + i * 1024] = hist[t + i * 1024];
}

// K1b: reduce nibble partials -> u32 out_deg (round-7-proven shape:
// 128 blocks x 1024 thr; 8 slices x 32 loads/thread; LDS combine; SWAR u8 lanes)
__global__ __launch_bounds__(1024) void k_reduce(
    const unsigned int* __restrict__ partial, unsigned int* __restrict__ out_deg)
{
    __shared__ unsigned int redE[8][128], redO[8][128];   // 8 KB
    int t = threadIdx.x;
    int wl = t & 127, gs = t >> 7;
    int w = blockIdx.x * 128 + wl;
    unsigned int accE = 0, accO = 0;
    #pragma unroll 8
    for (int i = 0; i < 32; i++) {
        unsigned int v = partial[(gs * 32 + i) * HWORDS + w];
        accE += v & 0x0F0F0F0Fu;
        accO += (v >> 4) & 0x0F0F0F0Fu;
    }
    redE[gs][wl] = accE;
    redO[gs][wl] = accO;
    __syncthreads();
    if (gs == 0) {
        unsigned int sE = 0, sO = 0;
        #pragma unroll
        for (int j = 0; j < 8; j++) { sE += redE[j][wl]; sO += redO[j][wl]; }
        uint4 lo = make_uint4(sE & 255u, sO & 255u, (sE >> 8) & 255u, (sO >> 8) & 255u);
        uint4 hi = make_uint4((sE >> 16) & 255u, (sO >> 16) & 255u, (sE >> 24) & 255u, (sO >> 24) & 255u);
        ((uint4*)(out_deg + 8 * w))[0] = lo;
        ((uint4*)(out_deg + 8 * w))[1] = hi;
    }
}

// K2 (fused aux, 528 blocks x 256): [0,512) compact+bitmap | [512,528) wprep
__global__ __launch_bounds__(256) void k_aux(
    const int* __restrict__ flag, int* __restrict__ loc,
    int* __restrict__ counters, unsigned long long* __restrict__ bitmap,
    const float* __restrict__ wlin, unsigned short* __restrict__ wswz)
{
    int b = blockIdx.x;
    int t = threadIdx.x;
    if (b < 512) {
        // ---- compact frontier F1 + membership bitmap ----
        __shared__ int cnt, gbase;
        if (t == 0) cnt = 0;
        __syncthreads();
        int v = b * 256 + t;
        int f = flag[v];
        unsigned long long m = __ballot(f != 0);
        if ((t & 63) == 0) bitmap[v >> 6] = m;
        int p = -1;
        if (f) p = atomicAdd(&cnt, 1);
        __syncthreads();
        if (t == 0) gbase = cnt ? atomicAdd(&counters[1], cnt) : 0;
        __syncthreads();
        int l = -1;
        if (p >= 0) {
            int id = gbase + p;
            if (id < F1CAP) l = id;
        }
        loc[v] = l;
    } else {
        // ---- pre-swizzle wlin into bf16 MFMA B-fragment order ----
        int g = (b - 512) * 256 + t;            // 4096 items
        int lane = g & 63, ct = (g >> 6) & 15, kt = g >> 10;
        int colbase = ct * 16 + (lane & 15);
        int kbase = kt * 32 + (lane >> 4) * 8;
        unsigned short o[8];
        #pragma unroll
        for (int i = 0; i < 8; i++) o[i] = f2bf(wlin[(kbase + i) * HID_K + colbase]);
        *(ushort4*)(wswz + g * 8)     = make_ushort4(o[0], o[1], o[2], o[3]);
        *(ushort4*)(wswz + g * 8 + 4) = make_ushort4(o[4], o[5], o[6], o[7]);
    }
}

// K3: select edges with dst in F1 (LDS bitmap) + inF1 histogram
__global__ __launch_bounds__(256) void k_e1_select(
    const int* __restrict__ src, const int* __restrict__ dst,
    const int* __restrict__ loc, const unsigned int* __restrict__ bitmap,
    int* __restrict__ counters,
    int* __restrict__ e1src, int* __restrict__ e1loc,
    int* __restrict__ inF1)
{
    __shared__ unsigned int bm[TOTAL_N / 32];   // 16 KB
    __shared__ int bsrc[E1BUF], bloc[E1BUF];
    __shared__ int cnt, gbase;
    int t = threadIdx.x;
    #pragma unroll
    for (int i = 0; i < 4; i++)
        ((uint4*)bm)[t + i * 256] = ((const uint4*)bitmap)[t + i * 256];
    if (t == 0) cnt = 0;
    __syncthreads();

    int ebase = blockIdx.x * EPB;
    const int4* d4p = (const int4*)(dst + ebase);
    #pragma unroll
    for (int i = 0; i < EPB / 1024; i++) {      // 2 iterations
        int4 d4 = d4p[i * 256 + t];
        int eidx = ebase + (i * 256 + t) * 4;
        int dd[4] = {d4.x, d4.y, d4.z, d4.w};
        #pragma unroll
        for (int j = 0; j < 4; j++) {
            int d = dd[j];
            if ((bm[d >> 5] >> (d & 31)) & 1u) {
                int l = loc[d];
                if (l >= 0) {
                    atomicAdd(&inF1[l], 1);
                    int s = src[eidx + j];
                    int p = atomicAdd(&cnt, 1);
                    if (p < E1BUF) { bsrc[p] = s; bloc[p] = l; }
                    else {
                        int gi = atomicAdd(&counters[2], 1);
                        if (gi < E1CAP) { e1src[gi] = s; e1loc[gi] = l; }
                    }
                }
            }
        }
    }
    __syncthreads();
    int c = min(cnt, E1BUF);
    if (t == 0) gbase = c ? atomicAdd(&counters[2], c) : 0;
    __syncthreads();
    if (t < c) {
        int i = gbase + t;
        if (i < E1CAP) { e1src[i] = bsrc[t]; e1loc[i] = bloc[t]; }
    }
}

// K3b: exclusive scan of inF1 -> cursor (single block)
__global__ __launch_bounds__(1024) void k_scan(
    const int* __restrict__ inF1, const int* __restrict__ counters,
    int* __restrict__ cursor)
{
    __shared__ int a[F1CAP], b[F1CAP];
    int nF1 = min(counters[1], F1CAP);
    int t = threadIdx.x;
    for (int i = t; i < F1CAP; i += 1024) a[i] = (i < nF1) ? inF1[i] : 0;
    __syncthreads();
    int* sp = a; int* dp = b;
    for (int off = 1; off < F1CAP; off <<= 1) {
        for (int i = t; i < F1CAP; i += 1024)
            dp[i] = (i >= off) ? sp[i] + sp[i - off] : sp[i];
        __syncthreads();
        int* tmp = sp; sp = dp; dp = tmp;
    }
    for (int i = t; i < F1CAP; i += 1024)
        cursor[i] = (i == 0) ? 0 : sp[i - 1];
}

// K3c: scatter edges into dst-sorted slots; pack (l<<17)|s
__global__ __launch_bounds__(256) void k_scatter(
    const int* __restrict__ e1src, const int* __restrict__ e1loc,
    const int* __restrict__ counters, int* __restrict__ cursor,
    int* __restrict__ es_pack)
{
    int i = blockIdx.x * 256 + threadIdx.x;
    int nE1 = min(counters[2], E1CAP);
    if (i >= nE1) return;
    int l = e1loc[i];
    int slot = atomicAdd(&cursor[l], 1);
    if (slot < E1CAP) es_pack[slot] = (l << 17) | e1src[i];
}

// K4: MFMA edge-GEMM + fused segmented reduce over sorted dst runs
__global__ __launch_bounds__(256) void k_h0agg(
    const float* __restrict__ x, const unsigned short* __restrict__ wswz,
    const float* __restrict__ blin, const int* __restrict__ es_pack,
    const unsigned int* __restrict__ out_deg, const int* __restrict__ counters,
    float* __restrict__ agg1)
{
    __shared__ unsigned short A[32][136];
    __shared__ float T[32][260];
    __shared__ float escs[32];
    __shared__ int rdst[32];
    __shared__ int rsrc[32];

    int nE1 = min(counters[2], E1CAP);
    int base = blockIdx.x * 32;
    if (base >= nE1) return;
    int t = threadIdx.x;
    int lane = t & 63, wq = t >> 6;

    if (t < 32) {
        int row = base + t;
        int s = -1, d = -1; float e = 0.f;
        if (row < nE1) {
            int pk = es_pack[row];
            s = pk & 0x1FFFF; d = pk >> 17;
            e = rsqrtf((float)max((int)out_deg[s], 1));
        }
        rsrc[t] = s; rdst[t] = d; escs[t] = e;
    }

    bf16x8 bfrag[4][4];
    #pragma unroll
    for (int kt = 0; kt < 4; kt++)
        #pragma unroll
        for (int n = 0; n < 4; n++) {
            int ct = wq * 4 + n;
            bfrag[kt][n] = *(const bf16x8*)(wswz + ((kt * 16 + ct) * 64 + lane) * 8);
        }

    __syncthreads();

    #pragma unroll
    for (int i = 0; i < 4; i++) {
        int idx = t + i * 256;
        int r = idx >> 5;
        int q = idx & 31;
        int s = rsrc[r];
        float4 v = make_float4(0.f, 0.f, 0.f, 0.f);
        if (s >= 0) v = ((const float4*)(x + (long long)s * IN_DIM_K))[q];
        ushort4 h;
        h.x = f2bf(v.x); h.y = f2bf(v.y); h.z = f2bf(v.z); h.w = f2bf(v.w);
        *(ushort4*)&A[r][q * 4] = h;
    }
    __syncthreads();

    f32x4 acc[2][4];
    #pragma unroll
    for (int m = 0; m < 2; m++)
        #pragma unroll
        for (int n = 0; n < 4; n++) acc[m][n] = (f32x4){0.f, 0.f, 0.f, 0.f};

    const unsigned short* Ab = &A[0][0];
    #pragma unroll
    for (int kt = 0; kt < 4; kt++) {
        bf16x8 a0 = *(const bf16x8*)(Ab + ((lane & 15) * 136 + kt * 32 + (lane >> 4) * 8));
        bf16x8 a1 = *(const bf16x8*)(Ab + (((lane & 15) + 16) * 136 + kt * 32 + (lane >> 4) * 8));
        #pragma unroll
        for (int n = 0; n < 4; n++) {
            acc[0][n] = __builtin_amdgcn_mfma_f32_16x16x32_bf16(a0, bfrag[kt][n], acc[0][n], 0, 0, 0);
            acc[1][n] = __builtin_amdgcn_mfma_f32_16x16x32_bf16(a1, bfrag[kt][n], acc[1][n], 0, 0, 0);
        }
    }

    int cbase = lane & 15;
    int rgrp = (lane >> 4) * 4;
    float bj[4];
    #pragma unroll
    for (int n = 0; n < 4; n++) bj[n] = blin[wq * 64 + n * 16 + cbase];
    #pragma unroll
    for (int m = 0; m < 2; m++)
        #pragma unroll
        for (int n = 0; n < 4; n++)
            #pragma unroll
            for (int j = 0; j < 4; j++) {
                int row = m * 16 + rgrp + j;
                int col = wq * 64 + n * 16 + cbase;
                T[row][col] = fmaxf(acc[m][n][j] + bj[n], 0.f) * escs[row];
            }
    __syncthreads();

    float segs = 0.f; int cur = rdst[0];
    #pragma unroll
    for (int r = 0; r < 32; r++) {
        int d = rdst[r];
        if (d != cur) {
            if (cur >= 0) atomicAdd(&agg1[cur * HID_K + t], segs);
            segs = 0.f; cur = d;
        }
        segs += T[r][t];
    }
    if (cur >= 0) atomicAdd(&agg1[cur * HID_K + t], segs);
}

// K5: h1[l] = relu((agg1[l]*in_norm)@w_c0 + b_c0)
__global__ __launch_bounds__(256) void k_h1(
    const float* __restrict__ agg1, const float* __restrict__ wc0,
    const float* __restrict__ bc0,
    const int* __restrict__ inF1,
    const int* __restrict__ counters, float* __restrict__ h1)
{
    __shared__ float as[16][HID_K];
    __shared__ float ns[16];

    int nF1 = min(counters[1], F1CAP);
    int base = blockIdx.x * 16;
    if (base >= nF1) return;
    int t = threadIdx.x;

    if (t < 16) {
        int l = base + t;
        ns[t] = (l < nF1) ? rsqrtf((float)max(inF1[l], 1)) : 0.f;
    }
    __syncthreads();

    #pragma unroll
    for (int i = 0; i < 4; i++) {
        int idx = t + i * 256;
        int e = idx >> 6;
        int q = idx & 63;
        int l = base + e;
        float4 v = make_float4(0.f, 0.f, 0.f, 0.f);
        if (l < nF1) v = ((const float4*)(agg1 + (long long)l * HID_K))[q];
        float sc = ns[e];
        v.x *= sc; v.y *= sc; v.z *= sc; v.w *= sc;
        ((float4*)as[e])[q] = v;
    }
    __syncthreads();

    float acc[16];
    #pragma unroll
    for (int e = 0; e < 16; e++) acc[e] = 0.f;

    int j = t;
    for (int k = 0; k < HID_K; k += 4) {
        float w0 = wc0[(k + 0) * HID_K + j];
        float w1 = wc0[(k + 1) * HID_K + j];
        float w2 = wc0[(k + 2) * HID_K + j];
        float w3 = wc0[(k + 3) * HID_K + j];
        #pragma unroll
        for (int e = 0; e < 16; e++) {
            float4 av = *(const float4*)&as[e][k];
            acc[e] = fmaf(av.x, w0, acc[e]);
            acc[e] = fmaf(av.y, w1, acc[e]);
            acc[e] = fmaf(av.z, w2, acc[e]);
            acc[e] = fmaf(av.w, w3, acc[e]);
        }
    }

    float bj = bc0[j];
    #pragma unroll
    for (int e = 0; e < 16; e++) {
        int l = base + e;
        if (l < nF1) h1[l * HID_K + j] = fmaxf(acc[e] + bj, 0.f);
    }
}

// K6: per agent: gather e0 list, aggregate h1, 2 GEMMs
__global__ __launch_bounds__(256) void k_final(
    const int* __restrict__ e0pack, const int* __restrict__ e0cnt,
    const int* __restrict__ loc, const unsigned int* __restrict__ out_deg,
    const float* __restrict__ h1,
    const float* __restrict__ wc1, const float* __restrict__ bc1,
    const float* __restrict__ wemb, const float* __restrict__ bemb,
    float* __restrict__ out)
{
    __shared__ float a_s[HID_K];
    __shared__ float h2[HID_K];
    __shared__ int   ls[APACK];
    __shared__ float scs[APACK];
    int a = blockIdx.x;
    int t = threadIdx.x;

    int n0 = e0cnt[a];
    int ne = min(n0, APACK);
    if (t < ne) {
        int s = e0pack[a * APACK + t];
        int l = loc[s];
        ls[t] = l;
        scs[t] = (l >= 0) ? rsqrtf((float)max((int)out_deg[s], 1)) : 0.f;
    }
    __syncthreads();

    float acc = 0.f;
    for (int i = 0; i < ne; i++) {
        int l = ls[i];
        if (l >= 0) acc = fmaf(scs[i], h1[(long long)l * HID_K + t], acc);
    }
    a_s[t] = acc * rsqrtf((float)max(n0, 1));
    __syncthreads();

    float h = 0.f;
    for (int k = 0; k < HID_K; k++)
        h = fmaf(a_s[k], wc1[k * HID_K + t], h);
    h2[t] = fmaxf(h + bc1[t], 0.f);
    __syncthreads();

    if (t < EMB_K) {
        float o = bemb[t];
        for (int k = 0; k < HID_K; k++)
            o = fmaf(h2[k], wemb[k * EMB_K + t], o);
        out[a * EMB_K + t] = o;
    }
}

extern "C" void kernel_launch(void* const* d_in, const int* in_sizes, int n_in,
                              void* d_out, int out_size, void* d_ws, size_t ws_size,
                              hipStream_t stream)
{
    const float* x    = (const float*)d_in[0];
    const int*   src  = (const int*)d_in[1];
    const int*   dst  = (const int*)d_in[2];
    const float* wlin = (const float*)d_in[5];
    const float* blin = (const float*)d_in[6];
    const float* wc0  = (const float*)d_in[7];
    const float* bc0  = (const float*)d_in[8];
    const float* wc1  = (const float*)d_in[9];
    const float* bc1  = (const float*)d_in[10];
    const float* wemb = (const float*)d_in[11];
    const float* bemb = (const float*)d_in[12];
    float* out = (float*)d_out;

    char* ws = (char*)d_ws;
    int*                counters = (int*)(ws + 0);
    int*                inF1     = (int*)(ws + 1024);
    int*                e0cnt    = (int*)(ws + 17408);
    int*                flag     = (int*)(ws + 65536);
    float*              agg1     = (float*)(ws + 589824);
    int*                loc      = (int*)(ws + 4784128);
    int*                e0pack   = (int*)(ws + 5308416);
    int*                e1src    = (int*)(ws + 5341184);
    int*                e1loc    = (int*)(ws + 5734400);
    unsigned int*       out_deg  = (unsigned int*)(ws + 6127616);
    unsigned short*     wswz     = (unsigned short*)(ws + 6651904);
    int*                cursor   = (int*)(ws + 6717440);
    unsigned long long* bitmap   = (unsigned long long*)(ws + 6733824);
    unsigned int*       partial  = (unsigned int*)(ws + 6750208);
    float*              h1       = (float*)(ws + 23527424);
    int*                es_pack  = (int*)(ws + 27721728);

    hipMemsetAsync(ws, 0, ZERO_SPAN, stream);

    k_outdeg_e0<<<G1, 1024, 0, stream>>>(src, dst, partial, flag, e0pack, e0cnt);
    k_reduce<<<HWORDS / 128, 1024, 0, stream>>>(partial, out_deg);
    k_aux<<<528, 256, 0, stream>>>(flag, loc, counters, bitmap, wlin, wswz);
    k_e1_select<<<SCAN_BLOCKS, 256, 0, stream>>>(src, dst, loc,
                                                 (const unsigned int*)bitmap,
                                                 counters, e1src, e1loc, inF1);
    k_scan<<<1, 1024, 0, stream>>>(inF1, counters, cursor);
    k_scatter<<<E1CAP / 256, 256, 0, stream>>>(e1src, e1loc, counters, cursor, es_pack);
    k_h0agg<<<E1CAP / 32, 256, 0, stream>>>(x, wswz, blin, es_pack, out_deg,
                                            counters, agg1);
    k_h1<<<F1CAP / 16, 256, 0, stream>>>(agg1, wc0, bc0, inF1, counters, h1);
    k_final<<<NAGENT, 256, 0, stream>>>(e0pack, e0cnt, loc, out_deg, h1,
                                        wc1, bc1, wemb, bemb, out);
}

// Round 10
// 136.527 us; speedup vs baseline: 2.4262x; 1.1194x over previous
//
#include <hip/hip_runtime.h>
#include <hip/hip_bf16.h>

#define TOTAL_N   131072
#define NEDGE     4194304
#define NPG       2048
#define IN_DIM_K  128
#define HID_K     256
#define EMB_K     64
#define NAGENT    64

#define F1CAP     4096
#define E1CAP     98304      // 1.5x expected nE1 (~65K)
#define APACK     128        // per-agent e0 slot cap (mean 32, Poisson tail safe)

#define G1        256                 // k_outdeg_e0 blocks (1/CU, full chip)
#define EPB1      (NEDGE / G1)        // 16384 edges per block
#define HWORDS    (TOTAL_N / 8)       // 16384 nibble-packed u32 words

#define SELB      256                 // k_e1_select blocks (persistent, 1/CU)
#define EPB       (NEDGE / SELB)      // 16384 edges per block
#define E1BUF     1024                // per-block hit buffer (mean 256, +48 sd)

// ---------------- workspace layout (bytes), ws_size = 256 MiB ----------------
// zeroed every launch [0, 4784128):
//   0        counters  int[256]        ([1]=nF1 [2]=nE1)
//   1024     inF1      int[F1CAP]      16K
//   17408    e0cnt     int[64]         256B  (= agent in-degree)
//   65536    flag      int[TOTAL_N]    512K
//   589824   agg1      float[F1CAP*HID] 4M
// not zeroed (fully written before read):
//   4784128  loc       int[TOTAL_N]    512K
//   5308416  e0pack    int[64*APACK]   32K
//   5341184  e1src     int[E1CAP]      384K
//   5734400  e1loc     int[E1CAP]      384K
//   6127616  out_deg   u32[TOTAL_N]    512K
//   6651904  wswz      u16[32768]      64K
//   6717440  cursor    int[F1CAP]      16K
//   6733824  bitmap    u64[2048]       16K
//   6750208  partial   u32[G1*HWORDS]  16M
//   23527424 h1        float[F1CAP*HID] 4M
//   27721728 es_pack   int[E1CAP]      384K
// total ~28.1 MB

#define ZERO_SPAN 4784128

typedef float f32x4 __attribute__((ext_vector_type(4)));
typedef short bf16x8 __attribute__((ext_vector_type(8)));

__device__ inline unsigned short f2bf(float f) {   // RNE f32->bf16
    unsigned int u = __float_as_uint(f);
    return (unsigned short)((u + 0x7FFFu + ((u >> 16) & 1u)) >> 16);
}

// K1: out-degree nibble histogram (full chip) + e0 select into per-agent buckets
__global__ __launch_bounds__(1024) void k_outdeg_e0(
    const int* __restrict__ src, const int* __restrict__ dst,
    unsigned int* __restrict__ partial,
    int* __restrict__ flag,
    int* __restrict__ e0pack, int* __restrict__ e0cnt)
{
    __shared__ unsigned int hist[HWORDS];   // 64 KB
    int t = threadIdx.x;
    #pragma unroll
    for (int i = 0; i < HWORDS / 1024; i++) hist[t + i * 1024] = 0u;
    __syncthreads();

    int ebase = blockIdx.x * EPB1;
    const int4* s4 = (const int4*)(src + ebase);
    const int4* d4 = (const int4*)(dst + ebase);
    #pragma unroll
    for (int i = 0; i < EPB1 / 4096; i++) {     // 4 iterations
        int4 sv = s4[i * 1024 + t];
        int4 dv = d4[i * 1024 + t];
        int ss[4] = {sv.x, sv.y, sv.z, sv.w};
        int dd[4] = {dv.x, dv.y, dv.z, dv.w};
        #pragma unroll
        for (int j = 0; j < 4; j++) {
            int s = ss[j], d = dd[j];
            atomicAdd(&hist[s >> 3], 1u << ((s & 7) * 4));
            if ((d & (NPG - 1)) == 0) {
                flag[s] = 1;                     // idempotent race
                int a = d >> 11;
                int slot = atomicAdd(&e0cnt[a], 1);   // 64 hot L2 addrs, ~2K total
                if (slot < APACK) e0pack[a * APACK + slot] = s;
            }
        }
    }
    __syncthreads();
    unsigned int* pout = partial + blockIdx.x * HWORDS;
    #pragma unroll
    for (int i = 0; i < HWORDS / 1024; i++) pout[t + i * 1024] = hist[t + i * 1024];
}

// K1b: reduce nibble partials -> u32 out_deg (128 blocks x 1024 thr;
// 8 slices x 32 loads/thread; LDS combine; SWAR u8 lanes)
__global__ __launch_bounds__(1024) void k_reduce(
    const unsigned int* __restrict__ partial, unsigned int* __restrict__ out_deg)
{
    __shared__ unsigned int redE[8][128], redO[8][128];   // 8 KB
    int t = threadIdx.x;
    int wl = t & 127, gs = t >> 7;
    int w = blockIdx.x * 128 + wl;
    unsigned int accE = 0, accO = 0;
    #pragma unroll 8
    for (int i = 0; i < 32; i++) {
        unsigned int v = partial[(gs * 32 + i) * HWORDS + w];
        accE += v & 0x0F0F0F0Fu;
        accO += (v >> 4) & 0x0F0F0F0Fu;
    }
    redE[gs][wl] = accE;
    redO[gs][wl] = accO;
    __syncthreads();
    if (gs == 0) {
        unsigned int sE = 0, sO = 0;
        #pragma unroll
        for (int j = 0; j < 8; j++) { sE += redE[j][wl]; sO += redO[j][wl]; }
        uint4 lo = make_uint4(sE & 255u, sO & 255u, (sE >> 8) & 255u, (sO >> 8) & 255u);
        uint4 hi = make_uint4((sE >> 16) & 255u, (sO >> 16) & 255u, (sE >> 24) & 255u, (sO >> 24) & 255u);
        ((uint4*)(out_deg + 8 * w))[0] = lo;
        ((uint4*)(out_deg + 8 * w))[1] = hi;
    }
}

// K2 (fused aux, 528 blocks x 256): [0,512) compact+bitmap | [512,528) wprep
__global__ __launch_bounds__(256) void k_aux(
    const int* __restrict__ flag, int* __restrict__ loc,
    int* __restrict__ counters, unsigned long long* __restrict__ bitmap,
    const float* __restrict__ wlin, unsigned short* __restrict__ wswz)
{
    int b = blockIdx.x;
    int t = threadIdx.x;
    if (b < 512) {
        // ---- compact frontier F1 + membership bitmap ----
        __shared__ int cnt, gbase;
        if (t == 0) cnt = 0;
        __syncthreads();
        int v = b * 256 + t;
        int f = flag[v];
        unsigned long long m = __ballot(f != 0);
        if ((t & 63) == 0) bitmap[v >> 6] = m;
        int p = -1;
        if (f) p = atomicAdd(&cnt, 1);
        __syncthreads();
        if (t == 0) gbase = cnt ? atomicAdd(&counters[1], cnt) : 0;
        __syncthreads();
        int l = -1;
        if (p >= 0) {
            int id = gbase + p;
            if (id < F1CAP) l = id;
        }
        loc[v] = l;
    } else {
        // ---- pre-swizzle wlin into bf16 MFMA B-fragment order ----
        int g = (b - 512) * 256 + t;            // 4096 items
        int lane = g & 63, ct = (g >> 6) & 15, kt = g >> 10;
        int colbase = ct * 16 + (lane & 15);
        int kbase = kt * 32 + (lane >> 4) * 8;
        unsigned short o[8];
        #pragma unroll
        for (int i = 0; i < 8; i++) o[i] = f2bf(wlin[(kbase + i) * HID_K + colbase]);
        *(ushort4*)(wswz + g * 8)     = make_ushort4(o[0], o[1], o[2], o[3]);
        *(ushort4*)(wswz + g * 8 + 4) = make_ushort4(o[4], o[5], o[6], o[7]);
    }
}

// K3: select edges with dst in F1 — persistent shape: 256 blocks x 1024 thr,
// one bitmap staging per block, 16 edges/thread, 1 counters[2] atomic per block
__global__ __launch_bounds__(1024) void k_e1_select(
    const int* __restrict__ src, const int* __restrict__ dst,
    const int* __restrict__ loc, const unsigned int* __restrict__ bitmap,
    int* __restrict__ counters,
    int* __restrict__ e1src, int* __restrict__ e1loc,
    int* __restrict__ inF1)
{
    __shared__ unsigned int bm[TOTAL_N / 32];   // 16 KB
    __shared__ int bsrc[E1BUF], bloc[E1BUF];    // 8 KB
    __shared__ int cnt, gbase;
    int t = threadIdx.x;
    ((uint4*)bm)[t] = ((const uint4*)bitmap)[t];   // 1024 uint4 = 16 KB
    if (t == 0) cnt = 0;
    __syncthreads();

    int ebase = blockIdx.x * EPB;
    const int4* d4p = (const int4*)(dst + ebase);
    #pragma unroll
    for (int i = 0; i < EPB / 4096; i++) {      // 4 iterations
        int4 d4 = d4p[i * 1024 + t];
        int eidx = ebase + (i * 1024 + t) * 4;
        int dd[4] = {d4.x, d4.y, d4.z, d4.w};
        #pragma unroll
        for (int j = 0; j < 4; j++) {
            int d = dd[j];
            if ((bm[d >> 5] >> (d & 31)) & 1u) {
                int l = loc[d];
                if (l >= 0) {
                    atomicAdd(&inF1[l], 1);
                    int s = src[eidx + j];
                    int p = atomicAdd(&cnt, 1);
                    if (p < E1BUF) { bsrc[p] = s; bloc[p] = l; }
                    else {
                        int gi = atomicAdd(&counters[2], 1);
                        if (gi < E1CAP) { e1src[gi] = s; e1loc[gi] = l; }
                    }
                }
            }
        }
    }
    __syncthreads();
    int c = min(cnt, E1BUF);
    if (t == 0) gbase = c ? atomicAdd(&counters[2], c) : 0;
    __syncthreads();
    if (t < c) {
        int i = gbase + t;
        if (i < E1CAP) { e1src[i] = bsrc[t]; e1loc[i] = bloc[t]; }
    }
}

// K3b: exclusive scan of inF1 -> cursor (single block)
__global__ __launch_bounds__(1024) void k_scan(
    const int* __restrict__ inF1, const int* __restrict__ counters,
    int* __restrict__ cursor)
{
    __shared__ int a[F1CAP], b[F1CAP];
    int nF1 = min(counters[1], F1CAP);
    int t = threadIdx.x;
    for (int i = t; i < F1CAP; i += 1024) a[i] = (i < nF1) ? inF1[i] : 0;
    __syncthreads();
    int* sp = a; int* dp = b;
    for (int off = 1; off < F1CAP; off <<= 1) {
        for (int i = t; i < F1CAP; i += 1024)
            dp[i] = (i >= off) ? sp[i] + sp[i - off] : sp[i];
        __syncthreads();
        int* tmp = sp; sp = dp; dp = tmp;
    }
    for (int i = t; i < F1CAP; i += 1024)
        cursor[i] = (i == 0) ? 0 : sp[i - 1];
}

// K3c: scatter edges into dst-sorted slots; pack (l<<17)|s
__global__ __launch_bounds__(256) void k_scatter(
    const int* __restrict__ e1src, const int* __restrict__ e1loc,
    const int* __restrict__ counters, int* __restrict__ cursor,
    int* __restrict__ es_pack)
{
    int i = blockIdx.x * 256 + threadIdx.x;
    int nE1 = min(counters[2], E1CAP);
    if (i >= nE1) return;
    int l = e1loc[i];
    int slot = atomicAdd(&cursor[l], 1);
    if (slot < E1CAP) es_pack[slot] = (l << 17) | e1src[i];
}

// K4: MFMA edge-GEMM + fused segmented reduce over sorted dst runs
__global__ __launch_bounds__(256) void k_h0agg(
    const float* __restrict__ x, const unsigned short* __restrict__ wswz,
    const float* __restrict__ blin, const int* __restrict__ es_pack,
    const unsigned int* __restrict__ out_deg, const int* __restrict__ counters,
    float* __restrict__ agg1)
{
    __shared__ unsigned short A[32][136];
    __shared__ float T[32][260];
    __shared__ float escs[32];
    __shared__ int rdst[32];
    __shared__ int rsrc[32];

    int nE1 = min(counters[2], E1CAP);
    int base = blockIdx.x * 32;
    if (base >= nE1) return;
    int t = threadIdx.x;
    int lane = t & 63, wq = t >> 6;

    if (t < 32) {
        int row = base + t;
        int s = -1, d = -1; float e = 0.f;
        if (row < nE1) {
            int pk = es_pack[row];
            s = pk & 0x1FFFF; d = pk >> 17;
            e = rsqrtf((float)max((int)out_deg[s], 1));
        }
        rsrc[t] = s; rdst[t] = d; escs[t] = e;
    }

    bf16x8 bfrag[4][4];
    #pragma unroll
    for (int kt = 0; kt < 4; kt++)
        #pragma unroll
        for (int n = 0; n < 4; n++) {
            int ct = wq * 4 + n;
            bfrag[kt][n] = *(const bf16x8*)(wswz + ((kt * 16 + ct) * 64 + lane) * 8);
        }

    __syncthreads();

    #pragma unroll
    for (int i = 0; i < 4; i++) {
        int idx = t + i * 256;
        int r = idx >> 5;
        int q = idx & 31;
        int s = rsrc[r];
        float4 v = make_float4(0.f, 0.f, 0.f, 0.f);
        if (s >= 0) v = ((const float4*)(x + (long long)s * IN_DIM_K))[q];
        ushort4 h;
        h.x = f2bf(v.x); h.y = f2bf(v.y); h.z = f2bf(v.z); h.w = f2bf(v.w);
        *(ushort4*)&A[r][q * 4] = h;
    }
    __syncthreads();

    f32x4 acc[2][4];
    #pragma unroll
    for (int m = 0; m < 2; m++)
        #pragma unroll
        for (int n = 0; n < 4; n++) acc[m][n] = (f32x4){0.f, 0.f, 0.f, 0.f};

    const unsigned short* Ab = &A[0][0];
    #pragma unroll
    for (int kt = 0; kt < 4; kt++) {
        bf16x8 a0 = *(const bf16x8*)(Ab + ((lane & 15) * 136 + kt * 32 + (lane >> 4) * 8));
        bf16x8 a1 = *(const bf16x8*)(Ab + (((lane & 15) + 16) * 136 + kt * 32 + (lane >> 4) * 8));
        #pragma unroll
        for (int n = 0; n < 4; n++) {
            acc[0][n] = __builtin_amdgcn_mfma_f32_16x16x32_bf16(a0, bfrag[kt][n], acc[0][n], 0, 0, 0);
            acc[1][n] = __builtin_amdgcn_mfma_f32_16x16x32_bf16(a1, bfrag[kt][n], acc[1][n], 0, 0, 0);
        }
    }

    int cbase = lane & 15;
    int rgrp = (lane >> 4) * 4;
    float bj[4];
    #pragma unroll
    for (int n = 0; n < 4; n++) bj[n] = blin[wq * 64 + n * 16 + cbase];
    #pragma unroll
    for (int m = 0; m < 2; m++)
        #pragma unroll
        for (int n = 0; n < 4; n++)
            #pragma unroll
            for (int j = 0; j < 4; j++) {
                int row = m * 16 + rgrp + j;
                int col = wq * 64 + n * 16 + cbase;
                T[row][col] = fmaxf(acc[m][n][j] + bj[n], 0.f) * escs[row];
            }
    __syncthreads();

    float segs = 0.f; int cur = rdst[0];
    #pragma unroll
    for (int r = 0; r < 32; r++) {
        int d = rdst[r];
        if (d != cur) {
            if (cur >= 0) atomicAdd(&agg1[cur * HID_K + t], segs);
            segs = 0.f; cur = d;
        }
        segs += T[r][t];
    }
    if (cur >= 0) atomicAdd(&agg1[cur * HID_K + t], segs);
}

// K5: h1[l] = relu((agg1[l]*in_norm)@w_c0 + b_c0)
__global__ __launch_bounds__(256) void k_h1(
    const float* __restrict__ agg1, const float* __restrict__ wc0,
    const float* __restrict__ bc0,
    const int* __restrict__ inF1,
    const int* __restrict__ counters, float* __restrict__ h1)
{
    __shared__ float as[16][HID_K];
    __shared__ float ns[16];

    int nF1 = min(counters[1], F1CAP);
    int base = blockIdx.x * 16;
    if (base >= nF1) return;
    int t = threadIdx.x;

    if (t < 16) {
        int l = base + t;
        ns[t] = (l < nF1) ? rsqrtf((float)max(inF1[l], 1)) : 0.f;
    }
    __syncthreads();

    #pragma unroll
    for (int i = 0; i < 4; i++) {
        int idx = t + i * 256;
        int e = idx >> 6;
        int q = idx & 63;
        int l = base + e;
        float4 v = make_float4(0.f, 0.f, 0.f, 0.f);
        if (l < nF1) v = ((const float4*)(agg1 + (long long)l * HID_K))[q];
        float sc = ns[e];
        v.x *= sc; v.y *= sc; v.z *= sc; v.w *= sc;
        ((float4*)as[e])[q] = v;
    }
    __syncthreads();

    float acc[16];
    #pragma unroll
    for (int e = 0; e < 16; e++) acc[e] = 0.f;

    int j = t;
    for (int k = 0; k < HID_K; k += 4) {
        float w0 = wc0[(k + 0) * HID_K + j];
        float w1 = wc0[(k + 1) * HID_K + j];
        float w2 = wc0[(k + 2) * HID_K + j];
        float w3 = wc0[(k + 3) * HID_K + j];
        #pragma unroll
        for (int e = 0; e < 16; e++) {
            float4 av = *(const float4*)&as[e][k];
            acc[e] = fmaf(av.x, w0, acc[e]);
            acc[e] = fmaf(av.y, w1, acc[e]);
            acc[e] = fmaf(av.z, w2, acc[e]);
            acc[e] = fmaf(av.w, w3, acc[e]);
        }
    }

    float bj = bc0[j];
    #pragma unroll
    for (int e = 0; e < 16; e++) {
        int l = base + e;
        if (l < nF1) h1[l * HID_K + j] = fmaxf(acc[e] + bj, 0.f);
    }
}

// K6: per agent: gather e0 list, aggregate h1, 2 GEMMs
__global__ __launch_bounds__(256) void k_final(
    const int* __restrict__ e0pack, const int* __restrict__ e0cnt,
    const int* __restrict__ loc, const unsigned int* __restrict__ out_deg,
    const float* __restrict__ h1,
    const float* __restrict__ wc1, const float* __restrict__ bc1,
    const float* __restrict__ wemb, const float* __restrict__ bemb,
    float* __restrict__ out)
{
    __shared__ float a_s[HID_K];
    __shared__ float h2[HID_K];
    __shared__ int   ls[APACK];
    __shared__ float scs[APACK];
    int a = blockIdx.x;
    int t = threadIdx.x;

    int n0 = e0cnt[a];
    int ne = min(n0, APACK);
    if (t < ne) {
        int s = e0pack[a * APACK + t];
        int l = loc[s];
        ls[t] = l;
        scs[t] = (l >= 0) ? rsqrtf((float)max((int)out_deg[s], 1)) : 0.f;
    }
    __syncthreads();

    float acc = 0.f;
    for (int i = 0; i < ne; i++) {
        int l = ls[i];
        if (l >= 0) acc = fmaf(scs[i], h1[(long long)l * HID_K + t], acc);
    }
    a_s[t] = acc * rsqrtf((float)max(n0, 1));
    __syncthreads();

    float h = 0.f;
    for (int k = 0; k < HID_K; k++)
        h = fmaf(a_s[k], wc1[k * HID_K + t], h);
    h2[t] = fmaxf(h + bc1[t], 0.f);
    __syncthreads();

    if (t < EMB_K) {
        float o = bemb[t];
        for (int k = 0; k < HID_K; k++)
            o = fmaf(h2[k], wemb[k * EMB_K + t], o);
        out[a * EMB_K + t] = o;
    }
}

extern "C" void kernel_launch(void* const* d_in, const int* in_sizes, int n_in,
                              void* d_out, int out_size, void* d_ws, size_t ws_size,
                              hipStream_t stream)
{
    const float* x    = (const float*)d_in[0];
    const int*   src  = (const int*)d_in[1];
    const int*   dst  = (const int*)d_in[2];
    const float* wlin = (const float*)d_in[5];
    const float* blin = (const float*)d_in[6];
    const float* wc0  = (const float*)d_in[7];
    const float* bc0  = (const float*)d_in[8];
    const float* wc1  = (const float*)d_in[9];
    const float* bc1  = (const float*)d_in[10];
    const float* wemb = (const float*)d_in[11];
    const float* bemb = (const float*)d_in[12];
    float* out = (float*)d_out;

    char* ws = (char*)d_ws;
    int*                counters = (int*)(ws + 0);
    int*                inF1     = (int*)(ws + 1024);
    int*                e0cnt    = (int*)(ws + 17408);
    int*                flag     = (int*)(ws + 65536);
    float*              agg1     = (float*)(ws + 589824);
    int*                loc      = (int*)(ws + 4784128);
    int*                e0pack   = (int*)(ws + 5308416);
    int*                e1src    = (int*)(ws + 5341184);
    int*                e1loc    = (int*)(ws + 5734400);
    unsigned int*       out_deg  = (unsigned int*)(ws + 6127616);
    unsigned short*     wswz     = (unsigned short*)(ws + 6651904);
    int*                cursor   = (int*)(ws + 6717440);
    unsigned long long* bitmap   = (unsigned long long*)(ws + 6733824);
    unsigned int*       partial  = (unsigned int*)(ws + 6750208);
    float*              h1       = (float*)(ws + 23527424);
    int*                es_pack  = (int*)(ws + 27721728);

    hipMemsetAsync(ws, 0, ZERO_SPAN, stream);

    k_outdeg_e0<<<G1, 1024, 0, stream>>>(src, dst, partial, flag, e0pack, e0cnt);
    k_reduce<<<HWORDS / 128, 1024, 0, stream>>>(partial, out_deg);
    k_aux<<<528, 256, 0, stream>>>(flag, loc, counters, bitmap, wlin, wswz);
    k_e1_select<<<SELB, 1024, 0, stream>>>(src, dst, loc,
                                           (const unsigned int*)bitmap,
                                           counters, e1src, e1loc, inF1);
    k_scan<<<1, 1024, 0, stream>>>(inF1, counters, cursor);
    k_scatter<<<E1CAP / 256, 256, 0, stream>>>(e1src, e1loc, counters, cursor, es_pack);
    k_h0agg<<<E1CAP / 32, 256, 0, stream>>>(x, wswz, blin, es_pack, out_deg,
                                            counters, agg1);
    k_h1<<<F1CAP / 16, 256, 0, stream>>>(agg1, wc0, bc0, inF1, counters, h1);
    k_final<<<NAGENT, 256, 0, stream>>>(e0pack, e0cnt, loc, out_deg, h1,
                                        wc1, bc1, wemb, bemb, out);
}

// Round 11
// 119.687 us; speedup vs baseline: 2.7675x; 1.1407x over previous
//
#include <hip/hip_runtime.h>
#include <hip/hip_bf16.h>

#define TOTAL_N   131072
#define NEDGE     4194304
#define NPG       2048
#define IN_DIM_K  128
#define HID_K     256
#define EMB_K     64
#define NAGENT    64

#define F1CAP     4096
#define APACK     128        // per-agent e0 slot cap
#define BCAP      96         // per-F1-node edge bucket cap (mean 32, P(>96)~1e-18)

#define G1        256                 // k_outdeg_e0 blocks
#define EPB1      (NEDGE / G1)        // 16384 edges per block
#define HWORDS    (TOTAL_N / 8)       // 16384 nibble-packed u32 words

#define SELB      256                 // k_e1_select blocks (persistent)
#define EPB       (NEDGE / SELB)      // 16384 edges per block

// ---------------- workspace layout (bytes) ----------------
// zeroed every launch [0, 589824):
//   0        counters  int[256]        ([1]=nF1)
//   1024     inF1      int[F1CAP]      16K   (in-degree of F1 nodes)
//   17408    e0cnt     int[64]         256B
//   65536    flag      int[TOTAL_N]    512K
// not zeroed (fully written before read):
//   589824   loc       int[TOTAL_N]    512K
//   1114112  e0pack    int[64*APACK]   32K
//   1146880  es_bucket int[F1CAP*BCAP] 1.5M  (slot<inF1[l] written)
//   2719744  out_deg   u32[TOTAL_N]    512K
//   3244032  wswz      u16[32768]      64K
//   3309568  h1        f32[F1CAP*HID]  4M
//   7503872  agg1      f32[F1CAP*HID]  4M
//   11698176 partial   u32[G1*HWORDS]  16M
//   28475392 bitmap    u64[2048]       16K
// total ~28.5 MB

#define ZERO_SPAN 589824

typedef float f32x4 __attribute__((ext_vector_type(4)));
typedef short bf16x8 __attribute__((ext_vector_type(8)));

__device__ inline unsigned short f2bf(float f) {   // RNE f32->bf16
    unsigned int u = __float_as_uint(f);
    return (unsigned short)((u + 0x7FFFu + ((u >> 16) & 1u)) >> 16);
}

// K1: out-degree nibble histogram (full chip) + e0 select into per-agent buckets
__global__ __launch_bounds__(1024) void k_outdeg_e0(
    const int* __restrict__ src, const int* __restrict__ dst,
    unsigned int* __restrict__ partial,
    int* __restrict__ flag,
    int* __restrict__ e0pack, int* __restrict__ e0cnt)
{
    __shared__ unsigned int hist[HWORDS];   // 64 KB
    int t = threadIdx.x;
    #pragma unroll
    for (int i = 0; i < HWORDS / 1024; i++) hist[t + i * 1024] = 0u;
    __syncthreads();

    int ebase = blockIdx.x * EPB1;
    const int4* s4 = (const int4*)(src + ebase);
    const int4* d4 = (const int4*)(dst + ebase);
    #pragma unroll
    for (int i = 0; i < EPB1 / 4096; i++) {     // 4 iterations
        int4 sv = s4[i * 1024 + t];
        int4 dv = d4[i * 1024 + t];
        int ss[4] = {sv.x, sv.y, sv.z, sv.w};
        int dd[4] = {dv.x, dv.y, dv.z, dv.w};
        #pragma unroll
        for (int j = 0; j < 4; j++) {
            int s = ss[j], d = dd[j];
            atomicAdd(&hist[s >> 3], 1u << ((s & 7) * 4));
            if ((d & (NPG - 1)) == 0) {
                flag[s] = 1;                     // idempotent race
                int a = d >> 11;
                int slot = atomicAdd(&e0cnt[a], 1);
                if (slot < APACK) e0pack[a * APACK + slot] = s;
            }
        }
    }
    __syncthreads();
    unsigned int* pout = partial + blockIdx.x * HWORDS;
    #pragma unroll
    for (int i = 0; i < HWORDS / 1024; i++) pout[t + i * 1024] = hist[t + i * 1024];
}

// K2 (merged aux+reduce, 260 blocks x 1024):
//   [0,128)   compact frontier (loc, bitmap) — r7-proven 1024-thr shape
//   [128,256) out_deg nibble reduce — r9/r10-proven shape verbatim
//   [256,260) wprep: wlin -> bf16 MFMA B-frag order
__global__ __launch_bounds__(1024) void k_auxred(
    const int* __restrict__ flag, int* __restrict__ loc,
    int* __restrict__ counters, unsigned long long* __restrict__ bitmap,
    const unsigned int* __restrict__ partial, unsigned int* __restrict__ out_deg,
    const float* __restrict__ wlin, unsigned short* __restrict__ wswz)
{
    int b = blockIdx.x;
    int t = threadIdx.x;
    if (b < 128) {
        __shared__ int cnt, gbase;
        if (t == 0) cnt = 0;
        __syncthreads();
        int v = b * 1024 + t;
        int f = flag[v];
        unsigned long long m = __ballot(f != 0);
        if ((t & 63) == 0) bitmap[v >> 6] = m;
        int p = -1;
        if (f) p = atomicAdd(&cnt, 1);
        __syncthreads();
        if (t == 0) gbase = cnt ? atomicAdd(&counters[1], cnt) : 0;
        __syncthreads();
        int l = -1;
        if (p >= 0) { int id = gbase + p; if (id < F1CAP) l = id; }
        loc[v] = l;
    } else if (b < 256) {
        __shared__ unsigned int redE[8][128], redO[8][128];   // 8 KB
        int wl = t & 127, gs = t >> 7;
        int w = (b - 128) * 128 + wl;
        unsigned int accE = 0, accO = 0;
        #pragma unroll 8
        for (int i = 0; i < 32; i++) {
            unsigned int v = partial[(gs * 32 + i) * HWORDS + w];
            accE += v & 0x0F0F0F0Fu;
            accO += (v >> 4) & 0x0F0F0F0Fu;
        }
        redE[gs][wl] = accE;
        redO[gs][wl] = accO;
        __syncthreads();
        if (gs == 0) {
            unsigned int sE = 0, sO = 0;
            #pragma unroll
            for (int j = 0; j < 8; j++) { sE += redE[j][wl]; sO += redO[j][wl]; }
            uint4 lo = make_uint4(sE & 255u, sO & 255u, (sE >> 8) & 255u, (sO >> 8) & 255u);
            uint4 hi = make_uint4((sE >> 16) & 255u, (sO >> 16) & 255u, (sE >> 24) & 255u, (sO >> 24) & 255u);
            ((uint4*)(out_deg + 8 * w))[0] = lo;
            ((uint4*)(out_deg + 8 * w))[1] = hi;
        }
    } else {
        int g = (b - 256) * 1024 + t;            // 4096 items
        int lane = g & 63, ct = (g >> 6) & 15, kt = g >> 10;
        int colbase = ct * 16 + (lane & 15);
        int kbase = kt * 32 + (lane >> 4) * 8;
        unsigned short o[8];
        #pragma unroll
        for (int i = 0; i < 8; i++) o[i] = f2bf(wlin[(kbase + i) * HID_K + colbase]);
        *(ushort4*)(wswz + g * 8)     = make_ushort4(o[0], o[1], o[2], o[3]);
        *(ushort4*)(wswz + g * 8 + 4) = make_ushort4(o[4], o[5], o[6], o[7]);
    }
}

// K3: select edges with dst in F1 — direct bucket scatter; slot atomic doubles
// as the inF1 in-degree count. Replaces sort (scan+scatter) entirely.
__global__ __launch_bounds__(1024) void k_e1_select(
    const int* __restrict__ src, const int* __restrict__ dst,
    const int* __restrict__ loc, const unsigned int* __restrict__ bitmap,
    int* __restrict__ inF1, int* __restrict__ es_bucket)
{
    __shared__ unsigned int bm[TOTAL_N / 32];   // 16 KB
    int t = threadIdx.x;
    ((uint4*)bm)[t] = ((const uint4*)bitmap)[t];   // 1024 uint4 = 16 KB
    __syncthreads();

    int ebase = blockIdx.x * EPB;
    const int4* d4p = (const int4*)(dst + ebase);
    #pragma unroll
    for (int i = 0; i < EPB / 4096; i++) {      // 4 iterations
        int4 d4 = d4p[i * 1024 + t];
        int eidx = ebase + (i * 1024 + t) * 4;
        int dd[4] = {d4.x, d4.y, d4.z, d4.w};
        #pragma unroll
        for (int j = 0; j < 4; j++) {
            int d = dd[j];
            if ((bm[d >> 5] >> (d & 31)) & 1u) {
                int l = loc[d];
                if (l >= 0) {
                    int slot = atomicAdd(&inF1[l], 1);   // count + slot in one
                    if (slot < BCAP) es_bucket[l * BCAP + slot] = src[eidx + j];
                }
            }
        }
    }
}

// K4: per-F1-node MFMA edge-GEMM; in-register shuffle row-sum; plain store.
// Block l: agg1[l] = sum_e out_norm[s_e] * relu(x[s_e] @ wlin + blin)
__global__ __launch_bounds__(256) void k_h0agg(
    const float* __restrict__ x, const unsigned short* __restrict__ wswz,
    const float* __restrict__ blin, const int* __restrict__ es_bucket,
    const unsigned int* __restrict__ out_deg, const int* __restrict__ inF1,
    const int* __restrict__ counters, float* __restrict__ agg1)
{
    __shared__ unsigned short A[32][136];   // 8.5 KB bf16 rows (pad: 2-way free)
    __shared__ float escs[32];
    __shared__ int rsrc[32];

    int nF1 = min(counters[1], F1CAP);
    int l = blockIdx.x;
    if (l >= nF1) return;
    int cnt = min(inF1[l], BCAP);
    int t = threadIdx.x;
    int lane = t & 63, wq = t >> 6;
    int cbase = lane & 15, rgrp = (lane >> 4) * 4;

    float bj[4];
    #pragma unroll
    for (int n = 0; n < 4; n++) bj[n] = blin[wq * 64 + n * 16 + cbase];

    float colacc[4] = {0.f, 0.f, 0.f, 0.f};
    int ntile = (cnt + 31) >> 5;

    for (int ti = 0; ti < ntile; ti++) {
        __syncthreads();     // prior iter finished reading A/escs
        if (t < 32) {
            int r = ti * 32 + t;
            int s = (r < cnt) ? es_bucket[l * BCAP + r] : -1;
            rsrc[t] = s;
            escs[t] = (s >= 0) ? rsqrtf((float)max((int)out_deg[s], 1)) : 0.f;
        }
        __syncthreads();
        #pragma unroll
        for (int i = 0; i < 4; i++) {        // gather 32 x-rows -> bf16 LDS
            int idx = t + i * 256;
            int r = idx >> 5, q = idx & 31;
            int s = rsrc[r];
            float4 v = make_float4(0.f, 0.f, 0.f, 0.f);
            if (s >= 0) v = ((const float4*)(x + (long long)s * IN_DIM_K))[q];
            ushort4 h;
            h.x = f2bf(v.x); h.y = f2bf(v.y); h.z = f2bf(v.z); h.w = f2bf(v.w);
            *(ushort4*)&A[r][q * 4] = h;
        }
        __syncthreads();

        f32x4 acc[2][4];
        #pragma unroll
        for (int m = 0; m < 2; m++)
            #pragma unroll
            for (int n = 0; n < 4; n++) acc[m][n] = (f32x4){0.f, 0.f, 0.f, 0.f};

        const unsigned short* Ab = &A[0][0];
        #pragma unroll
        for (int kt = 0; kt < 4; kt++) {
            bf16x8 a0 = *(const bf16x8*)(Ab + ((lane & 15) * 136 + kt * 32 + (lane >> 4) * 8));
            bf16x8 a1 = *(const bf16x8*)(Ab + (((lane & 15) + 16) * 136 + kt * 32 + (lane >> 4) * 8));
            #pragma unroll
            for (int n = 0; n < 4; n++) {
                bf16x8 bf = *(const bf16x8*)(wswz + ((kt * 16 + wq * 4 + n) * 64 + lane) * 8);
                acc[0][n] = __builtin_amdgcn_mfma_f32_16x16x32_bf16(a0, bf, acc[0][n], 0, 0, 0);
                acc[1][n] = __builtin_amdgcn_mfma_f32_16x16x32_bf16(a1, bf, acc[1][n], 0, 0, 0);
            }
        }

        // relu+scale+row-sum: all 32 rows share destination l
        #pragma unroll
        for (int n = 0; n < 4; n++) {
            float part = 0.f;
            #pragma unroll
            for (int m = 0; m < 2; m++)
                #pragma unroll
                for (int j = 0; j < 4; j++) {
                    int row = m * 16 + rgrp + j;
                    part += fmaxf(acc[m][n][j] + bj[n], 0.f) * escs[row];
                }
            part += __shfl_xor(part, 16);
            part += __shfl_xor(part, 32);
            colacc[n] += part;
        }
    }

    if (lane < 16) {
        #pragma unroll
        for (int n = 0; n < 4; n++)
            agg1[l * HID_K + wq * 64 + n * 16 + lane] = colacc[n];
    }
}

// K5: h1[l] = relu((agg1[l]*in_norm)@w_c0 + b_c0)
__global__ __launch_bounds__(256) void k_h1(
    const float* __restrict__ agg1, const float* __restrict__ wc0,
    const float* __restrict__ bc0,
    const int* __restrict__ inF1,
    const int* __restrict__ counters, float* __restrict__ h1)
{
    __shared__ float as[16][HID_K];
    __shared__ float ns[16];

    int nF1 = min(counters[1], F1CAP);
    int base = blockIdx.x * 16;
    if (base >= nF1) return;
    int t = threadIdx.x;

    if (t < 16) {
        int l = base + t;
        ns[t] = (l < nF1) ? rsqrtf((float)max(inF1[l], 1)) : 0.f;
    }
    __syncthreads();

    #pragma unroll
    for (int i = 0; i < 4; i++) {
        int idx = t + i * 256;
        int e = idx >> 6;
        int q = idx & 63;
        int l = base + e;
        float4 v = make_float4(0.f, 0.f, 0.f, 0.f);
        if (l < nF1) v = ((const float4*)(agg1 + (long long)l * HID_K))[q];
        float sc = ns[e];
        v.x *= sc; v.y *= sc; v.z *= sc; v.w *= sc;
        ((float4*)as[e])[q] = v;
    }
    __syncthreads();

    float acc[16];
    #pragma unroll
    for (int e = 0; e < 16; e++) acc[e] = 0.f;

    int j = t;
    for (int k = 0; k < HID_K; k += 4) {
        float w0 = wc0[(k + 0) * HID_K + j];
        float w1 = wc0[(k + 1) * HID_K + j];
        float w2 = wc0[(k + 2) * HID_K + j];
        float w3 = wc0[(k + 3) * HID_K + j];
        #pragma unroll
        for (int e = 0; e < 16; e++) {
            float4 av = *(const float4*)&as[e][k];
            acc[e] = fmaf(av.x, w0, acc[e]);
            acc[e] = fmaf(av.y, w1, acc[e]);
            acc[e] = fmaf(av.z, w2, acc[e]);
            acc[e] = fmaf(av.w, w3, acc[e]);
        }
    }

    float bj = bc0[j];
    #pragma unroll
    for (int e = 0; e < 16; e++) {
        int l = base + e;
        if (l < nF1) h1[l * HID_K + j] = fmaxf(acc[e] + bj, 0.f);
    }
}

// K6: per agent: gather e0 list, aggregate h1, 2 GEMMs
__global__ __launch_bounds__(256) void k_final(
    const int* __restrict__ e0pack, const int* __restrict__ e0cnt,
    const int* __restrict__ loc, const unsigned int* __restrict__ out_deg,
    const float* __restrict__ h1,
    const float* __restrict__ wc1, const float* __restrict__ bc1,
    const float* __restrict__ wemb, const float* __restrict__ bemb,
    float* __restrict__ out)
{
    __shared__ float a_s[HID_K];
    __shared__ float h2[HID_K];
    __shared__ int   ls[APACK];
    __shared__ float scs[APACK];
    int a = blockIdx.x;
    int t = threadIdx.x;

    int n0 = e0cnt[a];
    int ne = min(n0, APACK);
    if (t < ne) {
        int s = e0pack[a * APACK + t];
        int l = loc[s];
        ls[t] = l;
        scs[t] = (l >= 0) ? rsqrtf((float)max((int)out_deg[s], 1)) : 0.f;
    }
    __syncthreads();

    float acc = 0.f;
    for (int i = 0; i < ne; i++) {
        int l = ls[i];
        if (l >= 0) acc = fmaf(scs[i], h1[(long long)l * HID_K + t], acc);
    }
    a_s[t] = acc * rsqrtf((float)max(n0, 1));
    __syncthreads();

    float h = 0.f;
    for (int k = 0; k < HID_K; k++)
        h = fmaf(a_s[k], wc1[k * HID_K + t], h);
    h2[t] = fmaxf(h + bc1[t], 0.f);
    __syncthreads();

    if (t < EMB_K) {
        float o = bemb[t];
        for (int k = 0; k < HID_K; k++)
            o = fmaf(h2[k], wemb[k * EMB_K + t], o);
        out[a * EMB_K + t] = o;
    }
}

extern "C" void kernel_launch(void* const* d_in, const int* in_sizes, int n_in,
                              void* d_out, int out_size, void* d_ws, size_t ws_size,
                              hipStream_t stream)
{
    const float* x    = (const float*)d_in[0];
    const int*   src  = (const int*)d_in[1];
    const int*   dst  = (const int*)d_in[2];
    const float* wlin = (const float*)d_in[5];
    const float* blin = (const float*)d_in[6];
    const float* wc0  = (const float*)d_in[7];
    const float* bc0  = (const float*)d_in[8];
    const float* wc1  = (const float*)d_in[9];
    const float* bc1  = (const float*)d_in[10];
    const float* wemb = (const float*)d_in[11];
    const float* bemb = (const float*)d_in[12];
    float* out = (float*)d_out;

    char* ws = (char*)d_ws;
    int*                counters  = (int*)(ws + 0);
    int*                inF1      = (int*)(ws + 1024);
    int*                e0cnt     = (int*)(ws + 17408);
    int*                flag      = (int*)(ws + 65536);
    int*                loc       = (int*)(ws + 589824);
    int*                e0pack    = (int*)(ws + 1114112);
    int*                es_bucket = (int*)(ws + 1146880);
    unsigned int*       out_deg   = (unsigned int*)(ws + 2719744);
    unsigned short*     wswz      = (unsigned short*)(ws + 3244032);
    float*              h1        = (float*)(ws + 3309568);
    float*              agg1      = (float*)(ws + 7503872);
    unsigned int*       partial   = (unsigned int*)(ws + 11698176);
    unsigned long long* bitmap    = (unsigned long long*)(ws + 28475392);

    hipMemsetAsync(ws, 0, ZERO_SPAN, stream);

    k_outdeg_e0<<<G1, 1024, 0, stream>>>(src, dst, partial, flag, e0pack, e0cnt);
    k_auxred<<<260, 1024, 0, stream>>>(flag, loc, counters, bitmap,
                                       partial, out_deg, wlin, wswz);
    k_e1_select<<<SELB, 1024, 0, stream>>>(src, dst, loc,
                                           (const unsigned int*)bitmap,
                                           inF1, es_bucket);
    k_h0agg<<<F1CAP, 256, 0, stream>>>(x, wswz, blin, es_bucket, out_deg,
                                       inF1, counters, agg1);
    k_h1<<<F1CAP / 16, 256, 0, stream>>>(agg1, wc0, bc0, inF1, counters, h1);
    k_final<<<NAGENT, 256, 0, stream>>>(e0pack, e0cnt, loc, out_deg, h1,
                                        wc1, bc1, wemb, bemb, out);
}

// Round 12
// 118.299 us; speedup vs baseline: 2.8000x; 1.0117x over previous
//
#include <hip/hip_runtime.h>
#include <hip/hip_bf16.h>

#define TOTAL_N   131072
#define NEDGE     4194304
#define NPG       2048
#define IN_DIM_K  128
#define HID_K     256
#define EMB_K     64
#define NAGENT    64

#define F1CAP     4096
#define APACK     128        // per-agent e0 slot cap
#define BCAP      96         // per-F1-node edge bucket cap (mean 32, P(>96)~1e-18)
#define NL        8          // F1 nodes per k_h0h1 block

#define G1        256                 // k_outdeg_e0 blocks
#define EPB1      (NEDGE / G1)        // 16384 edges per block
#define HWORDS    (TOTAL_N / 8)       // 16384 nibble-packed u32 words

#define SELB      256                 // k_e1_select blocks (persistent)
#define EPB       (NEDGE / SELB)      // 16384 edges per block

// ---------------- workspace layout (bytes) ----------------
// zeroed every launch [0, 34048):
//   0        counters  int[256]        ([1]=nF1)
//   1024     inF1      int[F1CAP]      16K   (in-degree of F1 nodes)
//   17408    e0cnt     int[64]         256B
//   17664    bitmap    u32[4096]       16K   (F1 membership, atomicOr by k1)
// not zeroed (fully written before read):
//   65536    loc       int[TOTAL_N]    512K
//   589824   e0pack    int[64*APACK]   32K
//   622592   es_bucket int[F1CAP*BCAP] 1.5M  (slot<inF1[l] written)
//   2195456  out_deg   u32[TOTAL_N]    512K
//   2719744  wswz      u16[32768]      64K
//   2785280  h1        f32[F1CAP*HID]  4M
//   6979584  partial   u32[G1*HWORDS]  16M
// total ~22.7 MB

#define ZERO_SPAN 34048

typedef float f32x4 __attribute__((ext_vector_type(4)));
typedef short bf16x8 __attribute__((ext_vector_type(8)));

__device__ inline unsigned short f2bf(float f) {   // RNE f32->bf16
    unsigned int u = __float_as_uint(f);
    return (unsigned short)((u + 0x7FFFu + ((u >> 16) & 1u)) >> 16);
}

// K1: out-degree nibble histogram + e0 select + F1 bitmap marking (r7-proven)
__global__ __launch_bounds__(1024) void k_outdeg_e0(
    const int* __restrict__ src, const int* __restrict__ dst,
    unsigned int* __restrict__ partial,
    unsigned int* __restrict__ bitmap,
    int* __restrict__ e0pack, int* __restrict__ e0cnt)
{
    __shared__ unsigned int hist[HWORDS];   // 64 KB
    int t = threadIdx.x;
    #pragma unroll
    for (int i = 0; i < HWORDS / 1024; i++) hist[t + i * 1024] = 0u;
    __syncthreads();

    int ebase = blockIdx.x * EPB1;
    const int4* s4 = (const int4*)(src + ebase);
    const int4* d4 = (const int4*)(dst + ebase);
    #pragma unroll
    for (int i = 0; i < EPB1 / 4096; i++) {     // 4 iterations
        int4 sv = s4[i * 1024 + t];
        int4 dv = d4[i * 1024 + t];
        int ss[4] = {sv.x, sv.y, sv.z, sv.w};
        int dd[4] = {dv.x, dv.y, dv.z, dv.w};
        #pragma unroll
        for (int j = 0; j < 4; j++) {
            int s = ss[j], d = dd[j];
            atomicAdd(&hist[s >> 3], 1u << ((s & 7) * 4));
            if ((d & (NPG - 1)) == 0) {
                atomicOr(&bitmap[s >> 5], 1u << (s & 31));
                int a = d >> 11;
                int slot = atomicAdd(&e0cnt[a], 1);
                if (slot < APACK) e0pack[a * APACK + slot] = s;
            }
        }
    }
    __syncthreads();
    unsigned int* pout = partial + blockIdx.x * HWORDS;
    #pragma unroll
    for (int i = 0; i < HWORDS / 1024; i++) pout[t + i * 1024] = hist[t + i * 1024];
}

// K2 (merged aux+reduce, 260 blocks x 1024):
//   [0,128)   compact frontier from bitmap (r7-proven shape)
//   [128,256) out_deg nibble reduce (r9/r10-proven verbatim)
//   [256,260) wprep: wlin -> bf16 MFMA B-frag order
__global__ __launch_bounds__(1024) void k_auxred(
    const unsigned int* __restrict__ bitmap, int* __restrict__ loc,
    int* __restrict__ counters,
    const unsigned int* __restrict__ partial, unsigned int* __restrict__ out_deg,
    const float* __restrict__ wlin, unsigned short* __restrict__ wswz)
{
    int b = blockIdx.x;
    int t = threadIdx.x;
    if (b < 128) {
        __shared__ int cnt, gbase;
        if (t == 0) cnt = 0;
        __syncthreads();
        int v = b * 1024 + t;
        int f = (bitmap[v >> 5] >> (v & 31)) & 1u;
        int p = -1;
        if (f) p = atomicAdd(&cnt, 1);
        __syncthreads();
        if (t == 0) gbase = cnt ? atomicAdd(&counters[1], cnt) : 0;
        __syncthreads();
        int l = -1;
        if (p >= 0) { int id = gbase + p; if (id < F1CAP) l = id; }
        loc[v] = l;
    } else if (b < 256) {
        __shared__ unsigned int redE[8][128], redO[8][128];   // 8 KB
        int wl = t & 127, gs = t >> 7;
        int w = (b - 128) * 128 + wl;
        unsigned int accE = 0, accO = 0;
        #pragma unroll 8
        for (int i = 0; i < 32; i++) {
            unsigned int v = partial[(gs * 32 + i) * HWORDS + w];
            accE += v & 0x0F0F0F0Fu;
            accO += (v >> 4) & 0x0F0F0F0Fu;
        }
        redE[gs][wl] = accE;
        redO[gs][wl] = accO;
        __syncthreads();
        if (gs == 0) {
            unsigned int sE = 0, sO = 0;
            #pragma unroll
            for (int j = 0; j < 8; j++) { sE += redE[j][wl]; sO += redO[j][wl]; }
            uint4 lo = make_uint4(sE & 255u, sO & 255u, (sE >> 8) & 255u, (sO >> 8) & 255u);
            uint4 hi = make_uint4((sE >> 16) & 255u, (sO >> 16) & 255u, (sE >> 24) & 255u, (sO >> 24) & 255u);
            ((uint4*)(out_deg + 8 * w))[0] = lo;
            ((uint4*)(out_deg + 8 * w))[1] = hi;
        }
    } else {
        int g = (b - 256) * 1024 + t;            // 4096 items
        int lane = g & 63, ct = (g >> 6) & 15, kt = g >> 10;
        int colbase = ct * 16 + (lane & 15);
        int kbase = kt * 32 + (lane >> 4) * 8;
        unsigned short o[8];
        #pragma unroll
        for (int i = 0; i < 8; i++) o[i] = f2bf(wlin[(kbase + i) * HID_K + colbase]);
        *(ushort4*)(wswz + g * 8)     = make_ushort4(o[0], o[1], o[2], o[3]);
        *(ushort4*)(wswz + g * 8 + 4) = make_ushort4(o[4], o[5], o[6], o[7]);
    }
}

// K3: select edges with dst in F1 — direct bucket scatter; slot atomic doubles
// as the inF1 in-degree count.
__global__ __launch_bounds__(1024) void k_e1_select(
    const int* __restrict__ src, const int* __restrict__ dst,
    const int* __restrict__ loc, const unsigned int* __restrict__ bitmap,
    int* __restrict__ inF1, int* __restrict__ es_bucket)
{
    __shared__ unsigned int bm[TOTAL_N / 32];   // 16 KB
    int t = threadIdx.x;
    ((uint4*)bm)[t] = ((const uint4*)bitmap)[t];   // 1024 uint4 = 16 KB
    __syncthreads();

    int ebase = blockIdx.x * EPB;
    const int4* d4p = (const int4*)(dst + ebase);
    #pragma unroll
    for (int i = 0; i < EPB / 4096; i++) {      // 4 iterations
        int4 d4 = d4p[i * 1024 + t];
        int eidx = ebase + (i * 1024 + t) * 4;
        int dd[4] = {d4.x, d4.y, d4.z, d4.w};
        #pragma unroll
        for (int j = 0; j < 4; j++) {
            int d = dd[j];
            if ((bm[d >> 5] >> (d & 31)) & 1u) {
                int l = loc[d];
                if (l >= 0) {
                    int slot = atomicAdd(&inF1[l], 1);   // count + slot in one
                    if (slot < BCAP) es_bucket[l * BCAP + slot] = src[eidx + j];
                }
            }
        }
    }
}

// K4 (fused h0agg+h1): block owns NL=8 F1 nodes.
// Per l: agg[l] = sum_e out_norm[s_e]*relu(x[s_e]@wlin+blin)  (MFMA + shuffle rowsum)
// Then:  h1[l]  = relu((agg[l]*in_norm[l]) @ wc0 + bc0)        (LDS tile GEMM)
__global__ __launch_bounds__(256) void k_h0h1(
    const float* __restrict__ x, const unsigned short* __restrict__ wswz,
    const float* __restrict__ blin, const int* __restrict__ es_bucket,
    const unsigned int* __restrict__ out_deg, const int* __restrict__ inF1,
    const int* __restrict__ counters,
    const float* __restrict__ wc0, const float* __restrict__ bc0,
    float* __restrict__ h1)
{
    __shared__ unsigned short A[32][136];   // 8.5 KB bf16 gather tile
    __shared__ float as[NL][HID_K];         // 8 KB agg rows (in_norm applied)
    __shared__ float escs[32];
    __shared__ int rsrc[32];

    int nF1 = min(counters[1], F1CAP);
    int base = blockIdx.x * NL;
    if (base >= nF1) return;
    int t = threadIdx.x;
    int lane = t & 63, wq = t >> 6;
    int cbase = lane & 15, rgrp = (lane >> 4) * 4;

    // wlin B-fragments cached once for all NL nodes
    bf16x8 bfrag[4][4];
    #pragma unroll
    for (int kt = 0; kt < 4; kt++)
        #pragma unroll
        for (int n = 0; n < 4; n++)
            bfrag[kt][n] = *(const bf16x8*)(wswz + ((kt * 16 + wq * 4 + n) * 64 + lane) * 8);

    float bj[4];
    #pragma unroll
    for (int n = 0; n < 4; n++) bj[n] = blin[wq * 64 + n * 16 + cbase];

    for (int r = 0; r < NL; r++) {
        int l = base + r;
        int cnt = (l < nF1) ? min(inF1[l], BCAP) : 0;
        float colacc[4] = {0.f, 0.f, 0.f, 0.f};
        int ntile = (cnt + 31) >> 5;

        for (int ti = 0; ti < ntile; ti++) {
            __syncthreads();     // prior tile's A/escs fully consumed
            if (t < 32) {
                int rr = ti * 32 + t;
                int s = (rr < cnt) ? es_bucket[l * BCAP + rr] : -1;
                rsrc[t] = s;
                escs[t] = (s >= 0) ? rsqrtf((float)max((int)out_deg[s], 1)) : 0.f;
            }
            __syncthreads();
            #pragma unroll
            for (int i = 0; i < 4; i++) {        // gather 32 x-rows -> bf16 LDS
                int idx = t + i * 256;
                int rr = idx >> 5, q = idx & 31;
                int s = rsrc[rr];
                float4 v = make_float4(0.f, 0.f, 0.f, 0.f);
                if (s >= 0) v = ((const float4*)(x + (long long)s * IN_DIM_K))[q];
                ushort4 h;
                h.x = f2bf(v.x); h.y = f2bf(v.y); h.z = f2bf(v.z); h.w = f2bf(v.w);
                *(ushort4*)&A[rr][q * 4] = h;
            }
            __syncthreads();

            f32x4 acc[2][4];
            #pragma unroll
            for (int m = 0; m < 2; m++)
                #pragma unroll
                for (int n = 0; n < 4; n++) acc[m][n] = (f32x4){0.f, 0.f, 0.f, 0.f};

            const unsigned short* Ab = &A[0][0];
            #pragma unroll
            for (int kt = 0; kt < 4; kt++) {
                bf16x8 a0 = *(const bf16x8*)(Ab + ((lane & 15) * 136 + kt * 32 + (lane >> 4) * 8));
                bf16x8 a1 = *(const bf16x8*)(Ab + (((lane & 15) + 16) * 136 + kt * 32 + (lane >> 4) * 8));
                #pragma unroll
                for (int n = 0; n < 4; n++) {
                    acc[0][n] = __builtin_amdgcn_mfma_f32_16x16x32_bf16(a0, bfrag[kt][n], acc[0][n], 0, 0, 0);
                    acc[1][n] = __builtin_amdgcn_mfma_f32_16x16x32_bf16(a1, bfrag[kt][n], acc[1][n], 0, 0, 0);
                }
            }

            // relu+scale+row-sum (all 32 rows share destination l)
            #pragma unroll
            for (int n = 0; n < 4; n++) {
                float part = 0.f;
                #pragma unroll
                for (int m = 0; m < 2; m++)
                    #pragma unroll
                    for (int j = 0; j < 4; j++) {
                        int row = m * 16 + rgrp + j;
                        part += fmaxf(acc[m][n][j] + bj[n], 0.f) * escs[row];
                    }
                part += __shfl_xor(part, 16);
                part += __shfl_xor(part, 32);
                colacc[n] += part;
            }
        }

        // deposit in_norm-scaled agg row into LDS tile
        float ns = (l < nF1) ? rsqrtf((float)max(inF1[l], 1)) : 0.f;
        if (lane < 16) {
            #pragma unroll
            for (int n = 0; n < 4; n++)
                as[r][wq * 64 + n * 16 + lane] = colacc[n] * ns;
        }
    }
    __syncthreads();

    // second GEMM: h1[base+e] = relu(as[e] @ wc0 + bc0); thread t owns col t
    float acc8[NL];
    #pragma unroll
    for (int e = 0; e < NL; e++) acc8[e] = 0.f;
    int j = t;
    for (int k = 0; k < HID_K; k += 4) {
        float w0 = wc0[(k + 0) * HID_K + j];
        float w1 = wc0[(k + 1) * HID_K + j];
        float w2 = wc0[(k + 2) * HID_K + j];
        float w3 = wc0[(k + 3) * HID_K + j];
        #pragma unroll
        for (int e = 0; e < NL; e++) {
            float4 av = *(const float4*)&as[e][k];
            acc8[e] = fmaf(av.x, w0, acc8[e]);
            acc8[e] = fmaf(av.y, w1, acc8[e]);
            acc8[e] = fmaf(av.z, w2, acc8[e]);
            acc8[e] = fmaf(av.w, w3, acc8[e]);
        }
    }
    float bcj = bc0[j];
    #pragma unroll
    for (int e = 0; e < NL; e++) {
        int l = base + e;
        if (l < nF1) h1[(long long)l * HID_K + j] = fmaxf(acc8[e] + bcj, 0.f);
    }
}

// K5: per agent: gather e0 list, aggregate h1, 2 GEMMs
__global__ __launch_bounds__(256) void k_final(
    const int* __restrict__ e0pack, const int* __restrict__ e0cnt,
    const int* __restrict__ loc, const unsigned int* __restrict__ out_deg,
    const float* __restrict__ h1,
    const float* __restrict__ wc1, const float* __restrict__ bc1,
    const float* __restrict__ wemb, const float* __restrict__ bemb,
    float* __restrict__ out)
{
    __shared__ float a_s[HID_K];
    __shared__ float h2[HID_K];
    __shared__ int   ls[APACK];
    __shared__ float scs[APACK];
    int a = blockIdx.x;
    int t = threadIdx.x;

    int n0 = e0cnt[a];
    int ne = min(n0, APACK);
    if (t < ne) {
        int s = e0pack[a * APACK + t];
        int l = loc[s];
        ls[t] = l;
        scs[t] = (l >= 0) ? rsqrtf((float)max((int)out_deg[s], 1)) : 0.f;
    }
    __syncthreads();

    float acc = 0.f;
    for (int i = 0; i < ne; i++) {
        int l = ls[i];
        if (l >= 0) acc = fmaf(scs[i], h1[(long long)l * HID_K + t], acc);
    }
    a_s[t] = acc * rsqrtf((float)max(n0, 1));
    __syncthreads();

    float h = 0.f;
    for (int k = 0; k < HID_K; k++)
        h = fmaf(a_s[k], wc1[k * HID_K + t], h);
    h2[t] = fmaxf(h + bc1[t], 0.f);
    __syncthreads();

    if (t < EMB_K) {
        float o = bemb[t];
        for (int k = 0; k < HID_K; k++)
            o = fmaf(h2[k], wemb[k * EMB_K + t], o);
        out[a * EMB_K + t] = o;
    }
}

extern "C" void kernel_launch(void* const* d_in, const int* in_sizes, int n_in,
                              void* d_out, int out_size, void* d_ws, size_t ws_size,
                              hipStream_t stream)
{
    const float* x    = (const float*)d_in[0];
    const int*   src  = (const int*)d_in[1];
    const int*   dst  = (const int*)d_in[2];
    const float* wlin = (const float*)d_in[5];
    const float* blin = (const float*)d_in[6];
    const float* wc0  = (const float*)d_in[7];
    const float* bc0  = (const float*)d_in[8];
    const float* wc1  = (const float*)d_in[9];
    const float* bc1  = (const float*)d_in[10];
    const float* wemb = (const float*)d_in[11];
    const float* bemb = (const float*)d_in[12];
    float* out = (float*)d_out;

    char* ws = (char*)d_ws;
    int*            counters  = (int*)(ws + 0);
    int*            inF1      = (int*)(ws + 1024);
    int*            e0cnt     = (int*)(ws + 17408);
    unsigned int*   bitmap    = (unsigned int*)(ws + 17664);
    int*            loc       = (int*)(ws + 65536);
    int*            e0pack    = (int*)(ws + 589824);
    int*            es_bucket = (int*)(ws + 622592);
    unsigned int*   out_deg   = (unsigned int*)(ws + 2195456);
    unsigned short* wswz      = (unsigned short*)(ws + 2719744);
    float*          h1        = (float*)(ws + 2785280);
    unsigned int*   partial   = (unsigned int*)(ws + 6979584);

    hipMemsetAsync(ws, 0, ZERO_SPAN, stream);

    k_outdeg_e0<<<G1, 1024, 0, stream>>>(src, dst, partial, bitmap, e0pack, e0cnt);
    k_auxred<<<260, 1024, 0, stream>>>(bitmap, loc, counters,
                                       partial, out_deg, wlin, wswz);
    k_e1_select<<<SELB, 1024, 0, stream>>>(src, dst, loc, bitmap,
                                           inF1, es_bucket);
    k_h0h1<<<F1CAP / NL, 256, 0, stream>>>(x, wswz, blin, es_bucket, out_deg,
                                           inF1, counters, wc0, bc0, h1);
    k_final<<<NAGENT, 256, 0, stream>>>(e0pack, e0cnt, loc, out_deg, h1,
                                        wc1, bc1, wemb, bemb, out);
}